// Round 2
// baseline (9323.129 us; speedup 1.0000x reference)
//
#include <hip/hip_runtime.h>
#include <math.h>

// ---------------------------------------------------------------------------
// HAT block (HAB x6 + OCAB + conv) — fp32 reference-accurate implementation.
// Layout: everything channels-last (N_pix, C). Convs = 9-tap shifted GEMMs.
// ---------------------------------------------------------------------------

#define DEV __device__ __forceinline__

constexpr int HH   = 192;
constexpr int WW   = 192;
constexpr int NT   = HH * WW;     // 36864 tokens
constexpr int C    = 180;
constexpr int HEADS= 6;
constexpr int HD   = 30;
constexpr int WS   = 16;
constexpr int NWW  = WW / WS;     // 12 windows per row
constexpr int NWIN = (HH/WS)*(WW/WS); // 144
constexpr int NTW  = WS*WS;       // 256 tokens per window
constexpr int OWS  = 24;          // overlapping window size
constexpr int NKV  = OWS*OWS;     // 576 kv tokens per window
constexpr int CCH  = 60;          // compressed channels
constexpr int CSE  = 6;           // SE bottleneck = CC/(SQ/CR) = 60/10
constexpr int HID  = 360;         // mlp hidden
constexpr int DEPTH= 6;

// workspace offsets (in floats)
constexpr size_t OFF_X    = 0;
constexpr size_t OFF_A    = OFF_X    + (size_t)NT*C;     //  6,635,520
constexpr size_t OFF_B    = OFF_A    + (size_t)NT*C;     // 13,271,040
constexpr size_t OFF_COMP = OFF_B    + (size_t)NT*C;     // 19,906,560
constexpr size_t OFF_S    = OFF_COMP + (size_t)NT*CCH;   // 22,118,400
constexpr size_t OFF_G    = OFF_S    + 64;
constexpr size_t OFF_QKV  = OFF_G    + 64;               // 22,118,528 ; holds
// max(NT*540 = 19,906,560 , NWIN*NKV*360 = 29,859,840) -> end ~ 52.0M floats (208MB)

// window-ordered row r -> natural row (handles roll by `shift`)
DEV int win_to_nat(int r, int shift) {
  int w   = r >> 8;
  int pos = r & 255;
  int wh = w / NWW, ww = w - wh*NWW;
  int rh = wh*WS + (pos >> 4);
  int rw = ww*WS + (pos & 15);
  int sh = rh + shift; if (sh >= HH) sh -= HH;
  int sw = rw + shift; if (sw >= WW) sw -= WW;
  return sh*WW + sw;
}

// OCAB patch row gr (w*576 + t) -> natural window-ordered xn row, or -1 if pad
DEV int ocab_src_row(int gr) {
  int w = gr / NKV;
  int t = gr - w*NKV;
  int wh = w / NWW, ww = w - wh*NWW;
  int i = t / OWS, j = t - i*OWS;
  int gh = wh*WS - 4 + i;
  int gw = ww*WS - 4 + j;
  if ((unsigned)gh >= (unsigned)HH || (unsigned)gw >= (unsigned)WW) return -1;
  return (((gh >> 4)*NWW + (gw >> 4)) << 8) + ((gh & 15) << 4) + (gw & 15);
}

DEV float gelu_exact(float v) {
  return 0.5f * v * (1.0f + erff(v * 0.70710678118654752f));
}

// ---------------------------------------------------------------------------
// LayerNorm (+ optional window partition with roll). grid = NT blocks x 64.
// mode 0: out row r = LN(in row r). mode 1: out row r = LN(in row win_to_nat(r))
// ---------------------------------------------------------------------------
__global__ __launch_bounds__(64) void ln_kernel(
    const float* __restrict__ X, const float* __restrict__ gw,
    const float* __restrict__ gb, float* __restrict__ OUT,
    int mode, int shift)
{
  int r = blockIdx.x;
  int s = (mode == 1) ? win_to_nat(r, shift) : r;
  int lane = threadIdx.x;
  const float* xr = X + (size_t)s * C;
  float v0 = xr[lane];
  float v1 = xr[lane + 64];
  float v2 = (lane < C - 128) ? xr[lane + 128] : 0.f;
  float sum = v0 + v1 + v2;
  float sq  = v0*v0 + v1*v1 + v2*v2;
  #pragma unroll
  for (int off = 32; off > 0; off >>= 1) {
    sum += __shfl_down(sum, off);
    sq  += __shfl_down(sq,  off);
  }
  sum = __shfl(sum, 0);
  sq  = __shfl(sq,  0);
  float mu  = sum * (1.f / C);
  float var = sq * (1.f / C) - mu * mu;
  float inv = rsqrtf(var + 1e-5f);
  float* orow = OUT + (size_t)r * C;
  orow[lane]      = (v0 - mu) * inv * gw[lane]      + gb[lane];
  orow[lane + 64] = (v1 - mu) * inv * gw[lane + 64] + gb[lane + 64];
  if (lane < C - 128)
    orow[lane + 128] = (v2 - mu) * inv * gw[lane + 128] + gb[lane + 128];
}

// ---------------------------------------------------------------------------
// Generic tiled GEMM: OUT = X(M,K) @ W(K,N) + bias, with options.
// amap: 0 identity rows, 1 OCAB patch gather (zero rows for padding)
// emap: 0 identity rows, 1 window-reverse+roll scatter (shift)
// epi : 0 store, 1 gelu store, 2 OUT[dst] = RES[dst] + acc + bias
// grid = (ceil(N/64), M/64), 256 threads.
// ---------------------------------------------------------------------------
__global__ __launch_bounds__(256) void gemm_kernel(
    const float* __restrict__ X, const float* __restrict__ Wm,
    const float* __restrict__ bias, float* __restrict__ OUT,
    const float* __restrict__ RES,
    int M, int N, int K, int amap, int emap, int epi, int shift)
{
  constexpr int BM = 64, BN = 64, BK = 16;
  __shared__ float As[BK][BM];
  __shared__ float Bs[BK][BN];
  int tid  = threadIdx.x;
  int row0 = blockIdx.y * BM;
  int col0 = blockIdx.x * BN;
  float acc[4][4] = {};
  int tm = (tid & 15) * 4;
  int tn = (tid >> 4) * 4;
  int ac = tid & 15;         // A: k-col this thread stages
  int am = tid >> 4;         // A: base m-row
  int bn = tid & 63;         // B: n-col
  int bk = tid >> 6;         // B: base k-row

  for (int k0 = 0; k0 < K; k0 += BK) {
    #pragma unroll
    for (int j = 0; j < 4; ++j) {
      int m  = am + j * 16;
      int gr = row0 + m;
      int kk = k0 + ac;
      float v = 0.f;
      if (kk < K) {
        int sr = gr;
        if (amap == 1) sr = ocab_src_row(gr);
        if (sr >= 0) v = X[(size_t)sr * K + kk];
      }
      As[ac][m] = v;
    }
    #pragma unroll
    for (int j = 0; j < 4; ++j) {
      int kr = bk + j * 4;
      int kk = k0 + kr;
      int gc = col0 + bn;
      Bs[kr][bn] = (kk < K && gc < N) ? Wm[(size_t)kk * N + gc] : 0.f;
    }
    __syncthreads();
    #pragma unroll
    for (int kk = 0; kk < BK; ++kk) {
      float4 a4 = *(const float4*)&As[kk][tm];
      float4 b4 = *(const float4*)&Bs[kk][tn];
      float av[4] = {a4.x, a4.y, a4.z, a4.w};
      float bv[4] = {b4.x, b4.y, b4.z, b4.w};
      #pragma unroll
      for (int i = 0; i < 4; ++i)
        #pragma unroll
        for (int j = 0; j < 4; ++j)
          acc[i][j] += av[i] * bv[j];
    }
    __syncthreads();
  }

  #pragma unroll
  for (int i = 0; i < 4; ++i) {
    int r   = row0 + tm + i;
    int dst = (emap == 1) ? win_to_nat(r, shift) : r;
    #pragma unroll
    for (int j = 0; j < 4; ++j) {
      int col = col0 + tn + j;
      if (col < N) {
        float v = acc[i][j] + bias[col];
        if (epi == 1) v = gelu_exact(v);
        if (epi == 2) v += RES[(size_t)dst * N + col];
        OUT[(size_t)dst * N + col] = v;
      }
    }
  }
}

// ---------------------------------------------------------------------------
// 3x3 conv as 9-tap shifted GEMM on channels-last data.
// X: (NT, IC), Wc: (OC, IC, 3, 3), OUT: (NT, OC)
// scale: per-IC multiplier (SE gate) or nullptr; RES: residual (stride OC) or nullptr
// grid = (ceil(OC/64), NT/64), 256 threads.
// ---------------------------------------------------------------------------
__global__ __launch_bounds__(256) void conv9_kernel(
    const float* __restrict__ X, const float* __restrict__ Wc,
    const float* __restrict__ bias, const float* __restrict__ scale,
    const float* __restrict__ RES, float* __restrict__ OUT,
    int IC, int OC)
{
  constexpr int BM = 64, BN = 64, BK = 16;
  __shared__ float As[BK][BM];
  __shared__ float Bs[BK][BN];
  int tid  = threadIdx.x;
  int row0 = blockIdx.y * BM;
  int col0 = blockIdx.x * BN;
  float acc[4][4] = {};
  int tm = (tid & 15) * 4;
  int tn = (tid >> 4) * 4;
  int ac = tid & 15;
  int am = tid >> 4;
  int bn = tid & 63;
  int bk = tid >> 6;

  for (int tap = 0; tap < 9; ++tap) {
    int dy = tap / 3 - 1, dx = tap % 3 - 1;
    for (int k0 = 0; k0 < IC; k0 += BK) {
      #pragma unroll
      for (int j = 0; j < 4; ++j) {
        int m = am + j * 16;
        int p = row0 + m;
        int h = p / WW, w = p - h * WW;
        int hh = h + dy, ww2 = w + dx;
        int kk = k0 + ac;
        float v = 0.f;
        if (kk < IC && (unsigned)hh < (unsigned)HH && (unsigned)ww2 < (unsigned)WW) {
          v = X[(size_t)(hh * WW + ww2) * IC + kk];
          if (scale) v *= scale[kk];
        }
        As[ac][m] = v;
      }
      #pragma unroll
      for (int j = 0; j < 4; ++j) {
        int kr = bk + j * 4;
        int kk = k0 + kr;
        int oc = col0 + bn;
        Bs[kr][bn] = (kk < IC && oc < OC) ? Wc[((size_t)oc * IC + kk) * 9 + tap] : 0.f;
      }
      __syncthreads();
      #pragma unroll
      for (int kk = 0; kk < BK; ++kk) {
        float4 a4 = *(const float4*)&As[kk][tm];
        float4 b4 = *(const float4*)&Bs[kk][tn];
        float av[4] = {a4.x, a4.y, a4.z, a4.w};
        float bv[4] = {b4.x, b4.y, b4.z, b4.w};
        #pragma unroll
        for (int i = 0; i < 4; ++i)
          #pragma unroll
          for (int j = 0; j < 4; ++j)
            acc[i][j] += av[i] * bv[j];
      }
      __syncthreads();
    }
  }

  #pragma unroll
  for (int i = 0; i < 4; ++i) {
    int p = row0 + tm + i;
    #pragma unroll
    for (int j = 0; j < 4; ++j) {
      int oc = col0 + tn + j;
      if (oc < OC) {
        float v = acc[i][j] + bias[oc];
        if (RES) v += RES[(size_t)p * OC + oc];
        OUT[(size_t)p * OC + oc] = v;
      }
    }
  }
}

// ---------------------------------------------------------------------------
// Window MSA: one block per (window, head). 256 threads = 256 queries.
// QKV: (NT, 540) window-ordered [Q|K|V] heads-concatenated. relb: (961, HEADS).
// OUT: (NT, C) window-ordered.
// ---------------------------------------------------------------------------
__global__ __launch_bounds__(256) void win_attn_kernel(
    const float* __restrict__ QKV, const float* __restrict__ relb,
    float* __restrict__ OUT, int shift)
{
  __shared__ float ks[NTW * 32];
  __shared__ float vs[NTW * 32];
  __shared__ float rb[961];
  __shared__ unsigned char rg[NTW];
  int b = blockIdx.x;
  int w = b / HEADS, h = b - (b / HEADS) * HEADS;
  int t = threadIdx.x;
  const float* base = QKV + (size_t)(w * NTW) * 540;

  float q[HD], acc[HD];
  #pragma unroll
  for (int c = 0; c < HD; ++c) {
    q[c] = base[(size_t)t * 540 + h * HD + c];
    ks[t * 32 + c] = base[(size_t)t * 540 + 180 + h * HD + c];
    vs[t * 32 + c] = base[(size_t)t * 540 + 360 + h * HD + c];
    acc[c] = 0.f;
  }
  for (int i = t; i < 961; i += 256) rb[i] = relb[i * HEADS + h];

  int myreg = 0;
  if (shift > 0) {
    int wh = w / NWW, ww = w - wh * NWW;
    int rh = wh * WS + (t >> 4);
    int rw = ww * WS + (t & 15);
    int regh = (rh < HH - WS) ? 0 : (rh < HH - 8 ? 1 : 2);
    int regw = (rw < WW - WS) ? 0 : (rw < WW - 8 ? 1 : 2);
    myreg = regh * 3 + regw;
    rg[t] = (unsigned char)myreg;
  }
  __syncthreads();

  const float scl = 0.18257418583505536f;  // 1/sqrt(30)
  float mmax = -1e30f, l = 0.f;
  int qi = t >> 4, qj = t & 15;

  for (int ki = 0; ki < NTW; ++ki) {
    const float* kr = &ks[ki * 32];
    float s = 0.f;
    #pragma unroll
    for (int c = 0; c < HD; ++c) s += q[c] * kr[c];
    s *= scl;
    int kii = ki >> 4, kjj = ki & 15;
    s += rb[(qi - kii + 15) * 31 + (qj - kjj + 15)];
    if (shift > 0 && rg[ki] != (unsigned char)myreg) s -= 100.f;
    float nm   = fmaxf(mmax, s);
    float corr = __expf(mmax - nm);
    float p    = __expf(s - nm);
    l = l * corr + p;
    const float* vr = &vs[ki * 32];
    #pragma unroll
    for (int c = 0; c < HD; ++c) acc[c] = acc[c] * corr + p * vr[c];
    mmax = nm;
  }
  float inv = 1.f / l;
  float* o = OUT + (size_t)(w * NTW + t) * C + h * HD;
  #pragma unroll
  for (int c = 0; c < HD; ++c) o[c] = acc[c] * inv;
}

// ---------------------------------------------------------------------------
// OCAB attention: one block per (window, head). Q: (NT, C) window-ordered,
// KV: (144*576, 360) [K|V]. OUT: (NT, C) window-ordered. 576 keys in 4 chunks.
// ---------------------------------------------------------------------------
__global__ __launch_bounds__(256) void ocab_attn_kernel(
    const float* __restrict__ Q, const float* __restrict__ KV,
    float* __restrict__ OUT)
{
  constexpr int CH = 144;
  __shared__ float ks[CH * 32];
  __shared__ float vs[CH * 32];
  int b = blockIdx.x;
  int w = b / HEADS, h = b - (b / HEADS) * HEADS;
  int t = threadIdx.x;
  float q[HD], acc[HD];
  const float* qr = Q + (size_t)(w * NTW + t) * C + h * HD;
  #pragma unroll
  for (int c = 0; c < HD; ++c) { q[c] = qr[c]; acc[c] = 0.f; }
  float mmax = -1e30f, l = 0.f;
  const float scl = 0.18257418583505536f;

  for (int ch = 0; ch < NKV / CH; ++ch) {
    __syncthreads();
    for (int idx = t; idx < CH * HD; idx += 256) {
      int row = idx / HD, c = idx - row * HD;
      const float* kvrow = KV + (size_t)(w * NKV + ch * CH + row) * 360 + h * HD;
      ks[row * 32 + c] = kvrow[c];
      vs[row * 32 + c] = kvrow[180 + c];
    }
    __syncthreads();
    for (int kk = 0; kk < CH; ++kk) {
      const float* kr = &ks[kk * 32];
      float s = 0.f;
      #pragma unroll
      for (int c = 0; c < HD; ++c) s += q[c] * kr[c];
      s *= scl;
      float nm   = fmaxf(mmax, s);
      float corr = __expf(mmax - nm);
      float p    = __expf(s - nm);
      l = l * corr + p;
      const float* vr = &vs[kk * 32];
      #pragma unroll
      for (int c = 0; c < HD; ++c) acc[c] = acc[c] * corr + p * vr[c];
      mmax = nm;
    }
  }
  float inv = 1.f / l;
  float* o = OUT + (size_t)(w * NTW + t) * C + h * HD;
  #pragma unroll
  for (int c = 0; c < HD; ++c) o[c] = acc[c] * inv;
}

// ---------------------------------------------------------------------------
// Column mean of COMP (NT, 60) -> S[60]. grid = 60 blocks x 256.
// ---------------------------------------------------------------------------
__global__ __launch_bounds__(256) void colmean_kernel(
    const float* __restrict__ COMP, float* __restrict__ S)
{
  int c = blockIdx.x;
  float sum = 0.f;
  for (int p = threadIdx.x; p < NT; p += 256)
    sum += COMP[(size_t)p * CCH + c];
  #pragma unroll
  for (int off = 32; off > 0; off >>= 1) sum += __shfl_down(sum, off);
  __shared__ float red[4];
  if ((threadIdx.x & 63) == 0) red[threadIdx.x >> 6] = sum;
  __syncthreads();
  if (threadIdx.x == 0)
    S[c] = (red[0] + red[1] + red[2] + red[3]) * (1.f / NT);
}

// ---------------------------------------------------------------------------
// SE gate: G = sigmoid(relu(S @ ca1 + b1) @ ca2 + b2). 1 block x 64.
// ---------------------------------------------------------------------------
__global__ __launch_bounds__(64) void se_kernel(
    const float* __restrict__ S, const float* __restrict__ w1,
    const float* __restrict__ b1, const float* __restrict__ w2,
    const float* __restrict__ b2, float* __restrict__ G)
{
  __shared__ float hid[CSE];
  int t = threadIdx.x;
  if (t < CSE) {
    float a = b1[t];
    for (int c = 0; c < CCH; ++c) a += S[c] * w1[c * CSE + t];
    hid[t] = fmaxf(a, 0.f);
  }
  __syncthreads();
  if (t < CCH) {
    float a = b2[t];
    #pragma unroll
    for (int j = 0; j < CSE; ++j) a += hid[j] * w2[j * CCH + t];
    G[t] = 1.f / (1.f + __expf(-a));
  }
}

// ---------------------------------------------------------------------------

extern "C" void kernel_launch(void* const* d_in, const int* in_sizes, int n_in,
                              void* d_out, int out_size, void* d_ws, size_t ws_size,
                              hipStream_t stream) {
  const float* x_in   = (const float*)d_in[0];
  const float* n1w    = (const float*)d_in[1];
  const float* n1b    = (const float*)d_in[2];
  const float* qkvw   = (const float*)d_in[3];
  const float* qkvb   = (const float*)d_in[4];
  const float* relb   = (const float*)d_in[5];
  const float* projw  = (const float*)d_in[6];
  const float* projb  = (const float*)d_in[7];
  const float* ccw    = (const float*)d_in[8];
  const float* ccb    = (const float*)d_in[9];
  const float* ca1w   = (const float*)d_in[10];
  const float* ca1b   = (const float*)d_in[11];
  const float* ca2w   = (const float*)d_in[12];
  const float* ca2b   = (const float*)d_in[13];
  const float* cew    = (const float*)d_in[14];
  const float* ceb    = (const float*)d_in[15];
  const float* n2w    = (const float*)d_in[16];
  const float* n2b    = (const float*)d_in[17];
  const float* m1w    = (const float*)d_in[18];
  const float* m1b    = (const float*)d_in[19];
  const float* m2w    = (const float*)d_in[20];
  const float* m2b    = (const float*)d_in[21];
  const float* onw    = (const float*)d_in[22];
  const float* onb    = (const float*)d_in[23];
  const float* oqw    = (const float*)d_in[24];
  const float* oqb    = (const float*)d_in[25];
  const float* okvw   = (const float*)d_in[26];
  const float* okvb   = (const float*)d_in[27];
  const float* opw    = (const float*)d_in[28];
  const float* opb    = (const float*)d_in[29];
  const float* convw  = (const float*)d_in[30];
  const float* convb  = (const float*)d_in[31];

  float* ws   = (float*)d_ws;
  float* X    = ws + OFF_X;
  float* A    = ws + OFF_A;
  float* B    = ws + OFF_B;
  float* COMP = ws + OFF_COMP;
  float* S    = ws + OFF_S;
  float* G    = ws + OFF_G;
  float* QKV  = ws + OFF_QKV;   // also used as OCAB KV buffer

  (void)hipMemcpyAsync(X, x_in, (size_t)NT * C * sizeof(float),
                       hipMemcpyDeviceToDevice, stream);

  const int MB = NT / 64;  // 576 row-blocks

  for (int i = 0; i < DEPTH; ++i) {
    int shift = (i % 2 == 0) ? 0 : WS / 2;
    // 1. LN1 + roll + window partition: A = windows of LN(X)
    ln_kernel<<<NT, 64, 0, stream>>>(X, n1w + i*C, n1b + i*C, A, 1, shift);
    // 2. QKV = A @ qkv_w + qkv_b
    gemm_kernel<<<dim3(9, MB), 256, 0, stream>>>(
        A, qkvw + (size_t)i*C*3*C, qkvb + (size_t)i*3*C, QKV, nullptr,
        NT, 3*C, C, 0, 0, 0, 0);
    // 3. window MSA -> A (window-ordered)
    win_attn_kernel<<<NWIN*HEADS, 256, 0, stream>>>(
        QKV, relb + (size_t)i*961*HEADS, A, shift);
    // 4. X += window_reverse(A @ proj_w + proj_b)
    gemm_kernel<<<dim3(3, MB), 256, 0, stream>>>(
        A, projw + (size_t)i*C*C, projb + (size_t)i*C, X, X,
        NT, C, C, 0, 1, 2, shift);
    // 5. COMP = conv3x3(X; cc)   (180 -> 60)
    conv9_kernel<<<dim3(1, MB), 256, 0, stream>>>(
        X, ccw + (size_t)i*CCH*C*9, ccb + (size_t)i*CCH,
        nullptr, nullptr, COMP, C, CCH);
    // 6. S = mean(COMP); G = SE gate
    colmean_kernel<<<CCH, 256, 0, stream>>>(COMP, S);
    se_kernel<<<1, 64, 0, stream>>>(
        S, ca1w + (size_t)i*CCH*CSE, ca1b + (size_t)i*CSE,
        ca2w + (size_t)i*CSE*CCH, ca2b + (size_t)i*CCH, G);
    // 7. X += conv3x3(COMP * G; ce)   (60 -> 180)
    conv9_kernel<<<dim3(3, MB), 256, 0, stream>>>(
        COMP, cew + (size_t)i*C*CCH*9, ceb + (size_t)i*C,
        G, X, X, CCH, C);
    // 8. MLP: A = LN2(X); QKV = gelu(A@m1+b1); X += QKV@m2 + b2
    ln_kernel<<<NT, 64, 0, stream>>>(X, n2w + i*C, n2b + i*C, A, 0, 0);
    gemm_kernel<<<dim3(6, MB), 256, 0, stream>>>(
        A, m1w + (size_t)i*C*HID, m1b + (size_t)i*HID, QKV, nullptr,
        NT, HID, C, 0, 0, 1, 0);
    gemm_kernel<<<dim3(3, MB), 256, 0, stream>>>(
        QKV, m2w + (size_t)i*HID*C, m2b + (size_t)i*C, X, X,
        NT, C, HID, 0, 0, 2, 0);
  }

  // ---- OCAB ----
  // A = windows of LN(X) (no shift)
  ln_kernel<<<NT, 64, 0, stream>>>(X, onw, onb, A, 1, 0);
  // B = A @ q_w + q_b
  gemm_kernel<<<dim3(3, MB), 256, 0, stream>>>(
      A, oqw, oqb, B, nullptr, NT, C, C, 0, 0, 0, 0);
  // KV = gather(A) @ kv_w + kv_b   (82944 x 360)
  gemm_kernel<<<dim3(6, NWIN*NKV/64), 256, 0, stream>>>(
      A, okvw, okvb, QKV, nullptr, NWIN*NKV, 2*C, C, 1, 0, 0, 0);
  // attention -> A
  ocab_attn_kernel<<<NWIN*HEADS, 256, 0, stream>>>(B, QKV, A);
  // X += window_reverse(A @ p_w + p_b)
  gemm_kernel<<<dim3(3, MB), 256, 0, stream>>>(
      A, opw, opb, X, X, NT, C, C, 0, 1, 2, 0);

  // ---- final conv + global shortcut -> d_out ----
  conv9_kernel<<<dim3(3, MB), 256, 0, stream>>>(
      X, convw, convb, nullptr, x_in, (float*)d_out, C, C);
}

// Round 3
// 8732.735 us; speedup vs baseline: 1.0676x; 1.0676x over previous
//
#include <hip/hip_runtime.h>
#include <math.h>

// ---------------------------------------------------------------------------
// HAT block (HAB x6 + OCAB + conv) — fp32 I/O, f16 MFMA GEMM/conv cores.
// Layout: everything channels-last (N_pix, C). Convs = 9-tap halo-tile MFMA.
// ---------------------------------------------------------------------------

#define DEV __device__ __forceinline__

constexpr int HH   = 192;
constexpr int WW   = 192;
constexpr int NT   = HH * WW;     // 36864 tokens
constexpr int C    = 180;
constexpr int HEADS= 6;
constexpr int HD   = 30;
constexpr int WS   = 16;
constexpr int NWW  = WW / WS;     // 12 windows per row
constexpr int NWIN = (HH/WS)*(WW/WS); // 144
constexpr int NTW  = WS*WS;       // 256 tokens per window
constexpr int OWS  = 24;          // overlapping window size
constexpr int NKV  = OWS*OWS;     // 576 kv tokens per window
constexpr int CCH  = 60;          // compressed channels
constexpr int CSE  = 6;           // SE bottleneck
constexpr int HID  = 360;         // mlp hidden
constexpr int DEPTH= 6;

typedef _Float16 h8   __attribute__((ext_vector_type(8)));
typedef float    f32x4 __attribute__((ext_vector_type(4)));

// workspace offsets (in floats)
constexpr size_t OFF_X    = 0;
constexpr size_t OFF_A    = OFF_X    + (size_t)NT*C;
constexpr size_t OFF_B    = OFF_A    + (size_t)NT*C;
constexpr size_t OFF_COMP = OFF_B    + (size_t)NT*C;
constexpr size_t OFF_S    = OFF_COMP + (size_t)NT*CCH;
constexpr size_t OFF_G    = OFF_S    + 64;
constexpr size_t OFF_QKV  = OFF_G    + 64;   // also OCAB KV buffer

// window-ordered row r -> natural row (handles roll by `shift`)
DEV int win_to_nat(int r, int shift) {
  int w   = r >> 8;
  int pos = r & 255;
  int wh = w / NWW, ww = w - wh*NWW;
  int rh = wh*WS + (pos >> 4);
  int rw = ww*WS + (pos & 15);
  int sh = rh + shift; if (sh >= HH) sh -= HH;
  int sw = rw + shift; if (sw >= WW) sw -= WW;
  return sh*WW + sw;
}

// OCAB patch row gr (w*576 + t) -> natural window-ordered xn row, or -1 if pad
DEV int ocab_src_row(int gr) {
  int w = gr / NKV;
  int t = gr - w*NKV;
  int wh = w / NWW, ww = w - wh*NWW;
  int i = t / OWS, j = t - i*OWS;
  int gh = wh*WS - 4 + i;
  int gw = ww*WS - 4 + j;
  if ((unsigned)gh >= (unsigned)HH || (unsigned)gw >= (unsigned)WW) return -1;
  return (((gh >> 4)*NWW + (gw >> 4)) << 8) + ((gh & 15) << 4) + (gw & 15);
}

DEV float gelu_exact(float v) {
  return 0.5f * v * (1.0f + erff(v * 0.70710678118654752f));
}

// ---------------------------------------------------------------------------
// LayerNorm (+ optional window partition with roll). grid = NT blocks x 64.
// ---------------------------------------------------------------------------
__global__ __launch_bounds__(64) void ln_kernel(
    const float* __restrict__ X, const float* __restrict__ gw,
    const float* __restrict__ gb, float* __restrict__ OUT,
    int mode, int shift)
{
  int r = blockIdx.x;
  int s = (mode == 1) ? win_to_nat(r, shift) : r;
  int lane = threadIdx.x;
  const float* xr = X + (size_t)s * C;
  float v0 = xr[lane];
  float v1 = xr[lane + 64];
  float v2 = (lane < C - 128) ? xr[lane + 128] : 0.f;
  float sum = v0 + v1 + v2;
  float sq  = v0*v0 + v1*v1 + v2*v2;
  #pragma unroll
  for (int off = 32; off > 0; off >>= 1) {
    sum += __shfl_down(sum, off);
    sq  += __shfl_down(sq,  off);
  }
  sum = __shfl(sum, 0);
  sq  = __shfl(sq,  0);
  float mu  = sum * (1.f / C);
  float var = sq * (1.f / C) - mu * mu;
  float inv = rsqrtf(var + 1e-5f);
  float* orow = OUT + (size_t)r * C;
  orow[lane]      = (v0 - mu) * inv * gw[lane]      + gb[lane];
  orow[lane + 64] = (v1 - mu) * inv * gw[lane + 64] + gb[lane + 64];
  if (lane < C - 128)
    orow[lane + 128] = (v2 - mu) * inv * gw[lane + 128] + gb[lane + 128];
}

// ---------------------------------------------------------------------------
// MFMA f16 GEMM: OUT = X(M,K) @ W(K,N) + bias. 64x64x32 tile, 4 waves.
// Wave w computes rows [w*16, w*16+16) x all 64 cols (4 nb accumulators).
// A/B frag layout: [entity=lane&15][k=quad*8+j]; C/D: col=lane&15,row=quad*4+r.
// amap 1: OCAB patch gather. emap 1: window-reverse+roll scatter.
// epi: 0 store, 1 gelu, 2 residual-add.
// grid = (ceil(N/64), M/64), 256 threads.
// ---------------------------------------------------------------------------
__global__ __launch_bounds__(256) void gemm_mfma(
    const float* __restrict__ X, const float* __restrict__ Wm,
    const float* __restrict__ bias, float* __restrict__ OUT,
    const float* __restrict__ RES,
    int M, int N, int K, int amap, int emap, int epi, int shift)
{
  __shared__ _Float16 As[64][40];   // [m][k], inner padded 32->40 (20-bank stride)
  __shared__ _Float16 Bs[64][40];   // [n][k] (W transposed during staging)
  int tid  = threadIdx.x;
  int lane = tid & 63, wave = tid >> 6;
  int quad = lane >> 4, ln16 = lane & 15;
  int row0 = blockIdx.y * 64;
  int col0 = blockIdx.x * 64;

  f32x4 acc[4];
  #pragma unroll
  for (int nb = 0; nb < 4; ++nb)
    #pragma unroll
    for (int r = 0; r < 4; ++r) acc[nb][r] = 0.f;

  // A staging map: thread -> row ar, k-segment ak (8 elems)
  int ar = tid >> 2;
  int ak = (tid & 3) * 8;
  int gr = row0 + ar;
  int sr = (amap == 1) ? ocab_src_row(gr) : gr;
  const float* xrow = (sr >= 0) ? X + (size_t)sr * K : nullptr;
  // B staging map: thread -> col bn, k-segment bko (8 elems)
  int bn = tid & 63, bko = (tid >> 6) * 8;
  int gc = col0 + bn;

  int nch = (K + 31) / 32;
  for (int c = 0; c < nch; ++c) {
    int k0 = c * 32;
    // stage A
    {
      h8 av;
      int kb = k0 + ak;
      if (xrow && kb + 8 <= K) {
        float4 p0 = *(const float4*)(xrow + kb);
        float4 p1 = *(const float4*)(xrow + kb + 4);
        av[0]=(_Float16)p0.x; av[1]=(_Float16)p0.y; av[2]=(_Float16)p0.z; av[3]=(_Float16)p0.w;
        av[4]=(_Float16)p1.x; av[5]=(_Float16)p1.y; av[6]=(_Float16)p1.z; av[7]=(_Float16)p1.w;
      } else {
        #pragma unroll
        for (int j = 0; j < 8; ++j) {
          float v = (xrow && kb + j < K) ? xrow[kb + j] : 0.f;
          av[j] = (_Float16)v;
        }
      }
      *(h8*)&As[ar][ak] = av;
    }
    // stage B (transpose W into [n][k])
    {
      h8 bv;
      #pragma unroll
      for (int j = 0; j < 8; ++j) {
        int kk = k0 + bko + j;
        float v = (kk < K && gc < N) ? Wm[(size_t)kk * N + gc] : 0.f;
        bv[j] = (_Float16)v;
      }
      *(h8*)&Bs[bn][bko] = bv;
    }
    __syncthreads();
    h8 af = *(const h8*)&As[wave*16 + ln16][quad*8];
    #pragma unroll
    for (int nb = 0; nb < 4; ++nb) {
      h8 bf = *(const h8*)&Bs[nb*16 + ln16][quad*8];
      acc[nb] = __builtin_amdgcn_mfma_f32_16x16x32_f16(af, bf, acc[nb], 0, 0, 0);
    }
    __syncthreads();
  }

  // epilogue: D row = quad*4 + r (within wave's 16-row tile), col = nb*16+ln16
  #pragma unroll
  for (int r = 0; r < 4; ++r) {
    int m   = row0 + wave*16 + quad*4 + r;
    int dst = (emap == 1) ? win_to_nat(m, shift) : m;
    #pragma unroll
    for (int nb = 0; nb < 4; ++nb) {
      int n = col0 + nb*16 + ln16;
      if (n < N) {
        float v = acc[nb][r] + bias[n];
        if (epi == 1) v = gelu_exact(v);
        if (epi == 2) v += RES[(size_t)dst * N + n];
        OUT[(size_t)dst * N + n] = v;
      }
    }
  }
}

// ---------------------------------------------------------------------------
// MFMA f16 3x3 conv, channels-last. Block = 64 consecutive pixels of one image
// row x 64 output channels. Halo tile (3 rows x 66 px x 32 ch) staged once per
// k-chunk; all 9 taps computed from LDS. Weights (9 taps x 64 oc x 32 ic) in LDS.
// X:(NT,IC) Wc:(OC,IC,3,3) OUT:(NT,OC). scale: per-IC gate or null. RES or null.
// grid = (ceil(OC/64), NT/64), 256 threads.
// ---------------------------------------------------------------------------
__global__ __launch_bounds__(256) void conv9_mfma(
    const float* __restrict__ X, const float* __restrict__ Wc,
    const float* __restrict__ bias, const float* __restrict__ scale,
    const float* __restrict__ RES, float* __restrict__ OUT,
    int IC, int OC)
{
  __shared__ _Float16 hs[3][66][40];     // halo [row][px][ic], padded inner
  __shared__ _Float16 wsm[9][64][40];    // [tap][oc][ic]
  int tid  = threadIdx.x;
  int lane = tid & 63, wave = tid >> 6;
  int quad = lane >> 4, ln16 = lane & 15;
  int p0 = blockIdx.y * 64;
  int h  = p0 / WW;
  int w0 = p0 - h * WW;          // 64 | 192 -> whole block in one image row
  int col0 = blockIdx.x * 64;

  f32x4 acc[4];
  #pragma unroll
  for (int nb = 0; nb < 4; ++nb)
    #pragma unroll
    for (int r = 0; r < 4; ++r) acc[nb][r] = 0.f;

  int nch = (IC + 31) / 32;
  for (int c = 0; c < nch; ++c) {
    int k0 = c * 32;
    // stage halo: 3 rows x 66 px x 4 k-segments
    for (int idx = tid; idx < 3*66*4; idx += 256) {
      int r    = idx / (66*4);
      int rem  = idx - r*(66*4);
      int px   = rem >> 2;
      int ks   = (rem & 3) * 8;
      int gh = h - 1 + r, gw = w0 - 1 + px;
      h8 hv;
      #pragma unroll
      for (int j = 0; j < 8; ++j) hv[j] = (_Float16)0.f;
      if ((unsigned)gh < (unsigned)HH && (unsigned)gw < (unsigned)WW) {
        const float* src = X + (size_t)(gh*WW + gw) * IC;
        #pragma unroll
        for (int j = 0; j < 8; ++j) {
          int kk = k0 + ks + j;
          if (kk < IC) {
            float v = src[kk];
            if (scale) v *= scale[kk];
            hv[j] = (_Float16)v;
          }
        }
      }
      *(h8*)&hs[r][px][ks] = hv;
    }
    // stage weights: 9 taps x 64 oc x 4 k-segments
    for (int idx = tid; idx < 9*64*4; idx += 256) {
      int tap = idx >> 8;          // /256
      int rem = idx & 255;
      int oc  = rem >> 2;
      int ks  = (rem & 3) * 8;
      int goc = col0 + oc;
      h8 hv;
      #pragma unroll
      for (int j = 0; j < 8; ++j) hv[j] = (_Float16)0.f;
      if (goc < OC) {
        #pragma unroll
        for (int j = 0; j < 8; ++j) {
          int kk = k0 + ks + j;
          if (kk < IC) hv[j] = (_Float16)Wc[((size_t)goc * IC + kk) * 9 + tap];
        }
      }
      *(h8*)&wsm[tap][oc][ks] = hv;
    }
    __syncthreads();
    #pragma unroll
    for (int tap = 0; tap < 9; ++tap) {
      int dyy = tap / 3, dxt = tap % 3;
      h8 af = *(const h8*)&hs[dyy][wave*16 + ln16 + dxt][quad*8];
      #pragma unroll
      for (int nb = 0; nb < 4; ++nb) {
        h8 bf = *(const h8*)&wsm[tap][nb*16 + ln16][quad*8];
        acc[nb] = __builtin_amdgcn_mfma_f32_16x16x32_f16(af, bf, acc[nb], 0, 0, 0);
      }
    }
    __syncthreads();
  }

  #pragma unroll
  for (int r = 0; r < 4; ++r) {
    int p = p0 + wave*16 + quad*4 + r;
    #pragma unroll
    for (int nb = 0; nb < 4; ++nb) {
      int oc = col0 + nb*16 + ln16;
      if (oc < OC) {
        float v = acc[nb][r] + bias[oc];
        if (RES) v += RES[(size_t)p * OC + oc];
        OUT[(size_t)p * OC + oc] = v;
      }
    }
  }
}

// ---------------------------------------------------------------------------
// Window MSA: one block per (window, head). 256 threads = 256 queries.
// ---------------------------------------------------------------------------
__global__ __launch_bounds__(256) void win_attn_kernel(
    const float* __restrict__ QKV, const float* __restrict__ relb,
    float* __restrict__ OUT, int shift)
{
  __shared__ float ks[NTW * 32];
  __shared__ float vs[NTW * 32];
  __shared__ float rb[961];
  __shared__ unsigned char rg[NTW];
  int b = blockIdx.x;
  int w = b / HEADS, hd = b - (b / HEADS) * HEADS;
  int t = threadIdx.x;
  const float* base = QKV + (size_t)(w * NTW) * 540;

  float q[HD], acc[HD];
  #pragma unroll
  for (int c = 0; c < HD; ++c) {
    q[c] = base[(size_t)t * 540 + hd * HD + c];
    ks[t * 32 + c] = base[(size_t)t * 540 + 180 + hd * HD + c];
    vs[t * 32 + c] = base[(size_t)t * 540 + 360 + hd * HD + c];
    acc[c] = 0.f;
  }
  for (int i = t; i < 961; i += 256) rb[i] = relb[i * HEADS + hd];

  int myreg = 0;
  if (shift > 0) {
    int wh = w / NWW, ww = w - wh * NWW;
    int rh = wh * WS + (t >> 4);
    int rw = ww * WS + (t & 15);
    int regh = (rh < HH - WS) ? 0 : (rh < HH - 8 ? 1 : 2);
    int regw = (rw < WW - WS) ? 0 : (rw < WW - 8 ? 1 : 2);
    myreg = regh * 3 + regw;
    rg[t] = (unsigned char)myreg;
  }
  __syncthreads();

  const float scl = 0.18257418583505536f;  // 1/sqrt(30)
  float mmax = -1e30f, l = 0.f;
  int qi = t >> 4, qj = t & 15;

  for (int ki = 0; ki < NTW; ++ki) {
    const float* kr = &ks[ki * 32];
    float s = 0.f;
    #pragma unroll
    for (int c = 0; c < HD; ++c) s += q[c] * kr[c];
    s *= scl;
    int kii = ki >> 4, kjj = ki & 15;
    s += rb[(qi - kii + 15) * 31 + (qj - kjj + 15)];
    if (shift > 0 && rg[ki] != (unsigned char)myreg) s -= 100.f;
    float nm   = fmaxf(mmax, s);
    float corr = __expf(mmax - nm);
    float p    = __expf(s - nm);
    l = l * corr + p;
    const float* vr = &vs[ki * 32];
    #pragma unroll
    for (int c = 0; c < HD; ++c) acc[c] = acc[c] * corr + p * vr[c];
    mmax = nm;
  }
  float inv = 1.f / l;
  float* o = OUT + (size_t)(w * NTW + t) * C + hd * HD;
  #pragma unroll
  for (int c = 0; c < HD; ++c) o[c] = acc[c] * inv;
}

// ---------------------------------------------------------------------------
// OCAB attention: one block per (window, head).
// ---------------------------------------------------------------------------
__global__ __launch_bounds__(256) void ocab_attn_kernel(
    const float* __restrict__ Q, const float* __restrict__ KV,
    float* __restrict__ OUT)
{
  constexpr int CH = 144;
  __shared__ float ks[CH * 32];
  __shared__ float vs[CH * 32];
  int b = blockIdx.x;
  int w = b / HEADS, hd = b - (b / HEADS) * HEADS;
  int t = threadIdx.x;
  float q[HD], acc[HD];
  const float* qr = Q + (size_t)(w * NTW + t) * C + hd * HD;
  #pragma unroll
  for (int c = 0; c < HD; ++c) { q[c] = qr[c]; acc[c] = 0.f; }
  float mmax = -1e30f, l = 0.f;
  const float scl = 0.18257418583505536f;

  for (int ch = 0; ch < NKV / CH; ++ch) {
    __syncthreads();
    for (int idx = t; idx < CH * HD; idx += 256) {
      int row = idx / HD, c = idx - row * HD;
      const float* kvrow = KV + (size_t)(w * NKV + ch * CH + row) * 360 + hd * HD;
      ks[row * 32 + c] = kvrow[c];
      vs[row * 32 + c] = kvrow[180 + c];
    }
    __syncthreads();
    for (int kk = 0; kk < CH; ++kk) {
      const float* kr = &ks[kk * 32];
      float s = 0.f;
      #pragma unroll
      for (int c = 0; c < HD; ++c) s += q[c] * kr[c];
      s *= scl;
      float nm   = fmaxf(mmax, s);
      float corr = __expf(mmax - nm);
      float p    = __expf(s - nm);
      l = l * corr + p;
      const float* vr = &vs[kk * 32];
      #pragma unroll
      for (int c = 0; c < HD; ++c) acc[c] = acc[c] * corr + p * vr[c];
      mmax = nm;
    }
  }
  float inv = 1.f / l;
  float* o = OUT + (size_t)(w * NTW + t) * C + hd * HD;
  #pragma unroll
  for (int c = 0; c < HD; ++c) o[c] = acc[c] * inv;
}

// ---------------------------------------------------------------------------
__global__ __launch_bounds__(256) void colmean_kernel(
    const float* __restrict__ COMP, float* __restrict__ S)
{
  int c = blockIdx.x;
  float sum = 0.f;
  for (int p = threadIdx.x; p < NT; p += 256)
    sum += COMP[(size_t)p * CCH + c];
  #pragma unroll
  for (int off = 32; off > 0; off >>= 1) sum += __shfl_down(sum, off);
  __shared__ float red[4];
  if ((threadIdx.x & 63) == 0) red[threadIdx.x >> 6] = sum;
  __syncthreads();
  if (threadIdx.x == 0)
    S[c] = (red[0] + red[1] + red[2] + red[3]) * (1.f / NT);
}

__global__ __launch_bounds__(64) void se_kernel(
    const float* __restrict__ S, const float* __restrict__ w1,
    const float* __restrict__ b1, const float* __restrict__ w2,
    const float* __restrict__ b2, float* __restrict__ G)
{
  __shared__ float hid[CSE];
  int t = threadIdx.x;
  if (t < CSE) {
    float a = b1[t];
    for (int c = 0; c < CCH; ++c) a += S[c] * w1[c * CSE + t];
    hid[t] = fmaxf(a, 0.f);
  }
  __syncthreads();
  if (t < CCH) {
    float a = b2[t];
    #pragma unroll
    for (int j = 0; j < CSE; ++j) a += hid[j] * w2[j * CCH + t];
    G[t] = 1.f / (1.f + __expf(-a));
  }
}

// ---------------------------------------------------------------------------

extern "C" void kernel_launch(void* const* d_in, const int* in_sizes, int n_in,
                              void* d_out, int out_size, void* d_ws, size_t ws_size,
                              hipStream_t stream) {
  const float* x_in   = (const float*)d_in[0];
  const float* n1w    = (const float*)d_in[1];
  const float* n1b    = (const float*)d_in[2];
  const float* qkvw   = (const float*)d_in[3];
  const float* qkvb   = (const float*)d_in[4];
  const float* relb   = (const float*)d_in[5];
  const float* projw  = (const float*)d_in[6];
  const float* projb  = (const float*)d_in[7];
  const float* ccw    = (const float*)d_in[8];
  const float* ccb    = (const float*)d_in[9];
  const float* ca1w   = (const float*)d_in[10];
  const float* ca1b   = (const float*)d_in[11];
  const float* ca2w   = (const float*)d_in[12];
  const float* ca2b   = (const float*)d_in[13];
  const float* cew    = (const float*)d_in[14];
  const float* ceb    = (const float*)d_in[15];
  const float* n2w    = (const float*)d_in[16];
  const float* n2b    = (const float*)d_in[17];
  const float* m1w    = (const float*)d_in[18];
  const float* m1b    = (const float*)d_in[19];
  const float* m2w    = (const float*)d_in[20];
  const float* m2b    = (const float*)d_in[21];
  const float* onw    = (const float*)d_in[22];
  const float* onb    = (const float*)d_in[23];
  const float* oqw    = (const float*)d_in[24];
  const float* oqb    = (const float*)d_in[25];
  const float* okvw   = (const float*)d_in[26];
  const float* okvb   = (const float*)d_in[27];
  const float* opw    = (const float*)d_in[28];
  const float* opb    = (const float*)d_in[29];
  const float* convw  = (const float*)d_in[30];
  const float* convb  = (const float*)d_in[31];

  float* ws   = (float*)d_ws;
  float* X    = ws + OFF_X;
  float* A    = ws + OFF_A;
  float* B    = ws + OFF_B;
  float* COMP = ws + OFF_COMP;
  float* S    = ws + OFF_S;
  float* G    = ws + OFF_G;
  float* QKV  = ws + OFF_QKV;

  (void)hipMemcpyAsync(X, x_in, (size_t)NT * C * sizeof(float),
                       hipMemcpyDeviceToDevice, stream);

  const int MB = NT / 64;  // 576 row-blocks

  for (int i = 0; i < DEPTH; ++i) {
    int shift = (i % 2 == 0) ? 0 : WS / 2;
    // 1. LN1 + roll + window partition
    ln_kernel<<<NT, 64, 0, stream>>>(X, n1w + i*C, n1b + i*C, A, 1, shift);
    // 2. QKV = A @ qkv_w + qkv_b
    gemm_mfma<<<dim3(9, MB), 256, 0, stream>>>(
        A, qkvw + (size_t)i*C*3*C, qkvb + (size_t)i*3*C, QKV, nullptr,
        NT, 3*C, C, 0, 0, 0, 0);
    // 3. window MSA
    win_attn_kernel<<<NWIN*HEADS, 256, 0, stream>>>(
        QKV, relb + (size_t)i*961*HEADS, A, shift);
    // 4. X += window_reverse(A @ proj_w + proj_b)
    gemm_mfma<<<dim3(3, MB), 256, 0, stream>>>(
        A, projw + (size_t)i*C*C, projb + (size_t)i*C, X, X,
        NT, C, C, 0, 1, 2, shift);
    // 5. COMP = conv3x3(X; cc)   (180 -> 60)
    conv9_mfma<<<dim3(1, MB), 256, 0, stream>>>(
        X, ccw + (size_t)i*CCH*C*9, ccb + (size_t)i*CCH,
        nullptr, nullptr, COMP, C, CCH);
    // 6. SE gate
    colmean_kernel<<<CCH, 256, 0, stream>>>(COMP, S);
    se_kernel<<<1, 64, 0, stream>>>(
        S, ca1w + (size_t)i*CCH*CSE, ca1b + (size_t)i*CSE,
        ca2w + (size_t)i*CSE*CCH, ca2b + (size_t)i*CCH, G);
    // 7. X += conv3x3(COMP * G; ce)   (60 -> 180)
    conv9_mfma<<<dim3(3, MB), 256, 0, stream>>>(
        COMP, cew + (size_t)i*C*CCH*9, ceb + (size_t)i*C,
        G, X, X, CCH, C);
    // 8. MLP
    ln_kernel<<<NT, 64, 0, stream>>>(X, n2w + i*C, n2b + i*C, A, 0, 0);
    gemm_mfma<<<dim3(6, MB), 256, 0, stream>>>(
        A, m1w + (size_t)i*C*HID, m1b + (size_t)i*HID, QKV, nullptr,
        NT, HID, C, 0, 0, 1, 0);
    gemm_mfma<<<dim3(3, MB), 256, 0, stream>>>(
        QKV, m2w + (size_t)i*HID*C, m2b + (size_t)i*C, X, X,
        NT, C, HID, 0, 0, 2, 0);
  }

  // ---- OCAB ----
  ln_kernel<<<NT, 64, 0, stream>>>(X, onw, onb, A, 1, 0);
  gemm_mfma<<<dim3(3, MB), 256, 0, stream>>>(
      A, oqw, oqb, B, nullptr, NT, C, C, 0, 0, 0, 0);
  gemm_mfma<<<dim3(6, NWIN*NKV/64), 256, 0, stream>>>(
      A, okvw, okvb, QKV, nullptr, NWIN*NKV, 2*C, C, 1, 0, 0, 0);
  ocab_attn_kernel<<<NWIN*HEADS, 256, 0, stream>>>(B, QKV, A);
  gemm_mfma<<<dim3(3, MB), 256, 0, stream>>>(
      A, opw, opb, X, X, NT, C, C, 0, 1, 2, 0);

  // ---- final conv + global shortcut -> d_out ----
  conv9_mfma<<<dim3(3, MB), 256, 0, stream>>>(
      X, convw, convb, nullptr, x_in, (float*)d_out, C, C);
}

// Round 4
// 5423.570 us; speedup vs baseline: 1.7190x; 1.6101x over previous
//
#include <hip/hip_runtime.h>
#include <math.h>

// ---------------------------------------------------------------------------
// HAT block (HAB x6 + OCAB + conv) — fp32 I/O, f16 MFMA GEMM/conv cores.
// Conv weights pre-packed per launch into the LDS image layout (coalesced).
// ---------------------------------------------------------------------------

#define DEV __device__ __forceinline__

constexpr int HH   = 192;
constexpr int WW   = 192;
constexpr int NT   = HH * WW;     // 36864 tokens
constexpr int C    = 180;
constexpr int HEADS= 6;
constexpr int HD   = 30;
constexpr int WS   = 16;
constexpr int NWW  = WW / WS;     // 12
constexpr int NWIN = (HH/WS)*(WW/WS); // 144
constexpr int NTW  = WS*WS;       // 256
constexpr int OWS  = 24;
constexpr int NKV  = OWS*OWS;     // 576
constexpr int CCH  = 60;
constexpr int CSE  = 6;
constexpr int HID  = 360;
constexpr int DEPTH= 6;

typedef _Float16 h8   __attribute__((ext_vector_type(8)));
typedef float    f32x4 __attribute__((ext_vector_type(4)));

// packed conv-weight chunk image: [tap][oc 0..63][k 0..39] halfs
constexpr int PKCHUNK = 9 * 64 * 40;   // 23040 halfs per (col-block, k-chunk)

// workspace offsets (in floats)
constexpr size_t OFF_X    = 0;
constexpr size_t OFF_A    = OFF_X    + (size_t)NT*C;
constexpr size_t OFF_B    = OFF_A    + (size_t)NT*C;
constexpr size_t OFF_COMP = OFF_B    + (size_t)NT*C;
constexpr size_t OFF_S    = OFF_COMP + (size_t)NT*CCH;
constexpr size_t OFF_G    = OFF_S    + 64;
constexpr size_t OFF_QKV  = OFF_G    + 64;      // holds QKV (19.9M f) / OCAB KV (29.9M f)
// conv weight packs live in the QKV region tail (beyond NT*540 floats);
// OCAB kv-GEMM overwrites them, but they are dead by then. Final-conv pack is
// created after ocab_attn (KV dead) at the same spot.
constexpr size_t OFF_PKCC = OFF_QKV + (size_t)NT*540;          // 6 layers cc packs
constexpr size_t OFF_PKCE = OFF_PKCC + (6*6*PKCHUNK)/2;        // 6 layers ce packs (halfs->floats)

DEV int win_to_nat(int r, int shift) {
  int w   = r >> 8;
  int pos = r & 255;
  int wh = w / NWW, ww = w - wh*NWW;
  int rh = wh*WS + (pos >> 4);
  int rw = ww*WS + (pos & 15);
  int sh = rh + shift; if (sh >= HH) sh -= HH;
  int sw = rw + shift; if (sw >= WW) sw -= WW;
  return sh*WW + sw;
}

DEV int ocab_src_row(int gr) {
  int w = gr / NKV;
  int t = gr - w*NKV;
  int wh = w / NWW, ww = w - wh*NWW;
  int i = t / OWS, j = t - i*OWS;
  int gh = wh*WS - 4 + i;
  int gw = ww*WS - 4 + j;
  if ((unsigned)gh >= (unsigned)HH || (unsigned)gw >= (unsigned)WW) return -1;
  return (((gh >> 4)*NWW + (gw >> 4)) << 8) + ((gh & 15) << 4) + (gw & 15);
}

DEV float gelu_exact(float v) {
  return 0.5f * v * (1.0f + erff(v * 0.70710678118654752f));
}

// ---------------------------------------------------------------------------
// Conv weight pack: Wc (OC,IC,3,3) fp32 -> Wp f16 [(cb*nch+ch)][tap][oc64][k40]
// ---------------------------------------------------------------------------
__global__ __launch_bounds__(256) void pack_convw(
    const float* __restrict__ Wc, _Float16* __restrict__ Wp,
    int IC, int OC, int nch, int total)
{
  int idx = blockIdx.x * 256 + threadIdx.x;
  if (idx >= total) return;
  int kk = idx % 40;
  int r  = idx / 40;
  int oc = r & 63; r >>= 6;
  int tap = r % 9; r /= 9;
  int ch = r % nch; int cb = r / nch;
  float v = 0.f;
  int goc = cb*64 + oc, gk = ch*32 + kk;
  if (kk < 32 && goc < OC && gk < IC)
    v = Wc[((size_t)goc * IC + gk) * 9 + tap];
  Wp[idx] = (_Float16)v;
}

// ---------------------------------------------------------------------------
// LayerNorm (+ optional window partition with roll). grid = NT blocks x 64.
// ---------------------------------------------------------------------------
__global__ __launch_bounds__(64) void ln_kernel(
    const float* __restrict__ X, const float* __restrict__ gw,
    const float* __restrict__ gb, float* __restrict__ OUT,
    int mode, int shift)
{
  int r = blockIdx.x;
  int s = (mode == 1) ? win_to_nat(r, shift) : r;
  int lane = threadIdx.x;
  const float* xr = X + (size_t)s * C;
  float v0 = xr[lane];
  float v1 = xr[lane + 64];
  float v2 = (lane < C - 128) ? xr[lane + 128] : 0.f;
  float sum = v0 + v1 + v2;
  float sq  = v0*v0 + v1*v1 + v2*v2;
  #pragma unroll
  for (int off = 32; off > 0; off >>= 1) {
    sum += __shfl_down(sum, off);
    sq  += __shfl_down(sq,  off);
  }
  sum = __shfl(sum, 0);
  sq  = __shfl(sq,  0);
  float mu  = sum * (1.f / C);
  float var = sq * (1.f / C) - mu * mu;
  float inv = rsqrtf(var + 1e-5f);
  float* orow = OUT + (size_t)r * C;
  orow[lane]      = (v0 - mu) * inv * gw[lane]      + gb[lane];
  orow[lane + 64] = (v1 - mu) * inv * gw[lane + 64] + gb[lane + 64];
  if (lane < C - 128)
    orow[lane + 128] = (v2 - mu) * inv * gw[lane + 128] + gb[lane + 128];
}

// ---------------------------------------------------------------------------
// MFMA f16 GEMM: OUT = X(M,K) @ W(K,N) + bias. 64x64x32 tile, 4 waves.
// ---------------------------------------------------------------------------
__global__ __launch_bounds__(256) void gemm_mfma(
    const float* __restrict__ X, const float* __restrict__ Wm,
    const float* __restrict__ bias, float* __restrict__ OUT,
    const float* __restrict__ RES,
    int M, int N, int K, int amap, int emap, int epi, int shift)
{
  __shared__ _Float16 As[64][40];
  __shared__ _Float16 Bs[64][40];
  int tid  = threadIdx.x;
  int lane = tid & 63, wave = tid >> 6;
  int quad = lane >> 4, ln16 = lane & 15;
  int row0 = blockIdx.y * 64;
  int col0 = blockIdx.x * 64;

  f32x4 acc[4];
  #pragma unroll
  for (int nb = 0; nb < 4; ++nb)
    #pragma unroll
    for (int r = 0; r < 4; ++r) acc[nb][r] = 0.f;

  int ar = tid >> 2;
  int ak = (tid & 3) * 8;
  int gr = row0 + ar;
  int sr = (amap == 1) ? ocab_src_row(gr) : gr;
  const float* xrow = (sr >= 0) ? X + (size_t)sr * K : nullptr;
  int bn = tid & 63, bko = (tid >> 6) * 8;
  int gc = col0 + bn;

  int nch = (K + 31) / 32;
  for (int c = 0; c < nch; ++c) {
    int k0 = c * 32;
    {
      h8 av;
      int kb = k0 + ak;
      if (xrow && kb + 8 <= K) {
        float4 p0 = *(const float4*)(xrow + kb);
        float4 p1 = *(const float4*)(xrow + kb + 4);
        av[0]=(_Float16)p0.x; av[1]=(_Float16)p0.y; av[2]=(_Float16)p0.z; av[3]=(_Float16)p0.w;
        av[4]=(_Float16)p1.x; av[5]=(_Float16)p1.y; av[6]=(_Float16)p1.z; av[7]=(_Float16)p1.w;
      } else {
        #pragma unroll
        for (int j = 0; j < 8; ++j) {
          float v = (xrow && kb + j < K) ? xrow[kb + j] : 0.f;
          av[j] = (_Float16)v;
        }
      }
      *(h8*)&As[ar][ak] = av;
    }
    {
      h8 bv;
      #pragma unroll
      for (int j = 0; j < 8; ++j) {
        int kk = k0 + bko + j;
        float v = (kk < K && gc < N) ? Wm[(size_t)kk * N + gc] : 0.f;
        bv[j] = (_Float16)v;
      }
      *(h8*)&Bs[bn][bko] = bv;
    }
    __syncthreads();
    h8 af = *(const h8*)&As[wave*16 + ln16][quad*8];
    #pragma unroll
    for (int nb = 0; nb < 4; ++nb) {
      h8 bf = *(const h8*)&Bs[nb*16 + ln16][quad*8];
      acc[nb] = __builtin_amdgcn_mfma_f32_16x16x32_f16(af, bf, acc[nb], 0, 0, 0);
    }
    __syncthreads();
  }

  #pragma unroll
  for (int r = 0; r < 4; ++r) {
    int m   = row0 + wave*16 + quad*4 + r;
    int dst = (emap == 1) ? win_to_nat(m, shift) : m;
    #pragma unroll
    for (int nb = 0; nb < 4; ++nb) {
      int n = col0 + nb*16 + ln16;
      if (n < N) {
        float v = acc[nb][r] + bias[n];
        if (epi == 1) v = gelu_exact(v);
        if (epi == 2) v += RES[(size_t)dst * N + n];
        OUT[(size_t)dst * N + n] = v;
      }
    }
  }
}

// ---------------------------------------------------------------------------
// MFMA f16 3x3 conv, channels-last, packed weights.
// Block = 64 consecutive pixels of one image row x 64 output channels.
// Wp: packed [(cb*nch+ch)][tap][oc64][k40] f16. Staging = contiguous h8 copy.
// grid = (ceil(OC/64), NT/64), 256 threads.
// ---------------------------------------------------------------------------
__global__ __launch_bounds__(256) void conv9_mfma(
    const float* __restrict__ X, const _Float16* __restrict__ Wp,
    const float* __restrict__ bias, const float* __restrict__ scale,
    const float* __restrict__ RES, float* __restrict__ OUT,
    int IC, int OC)
{
  __shared__ _Float16 hs[3][66][40];     // halo [row][px][ic]
  __shared__ _Float16 wsm[PKCHUNK];      // [tap][oc][k]
  int tid  = threadIdx.x;
  int lane = tid & 63, wave = tid >> 6;
  int quad = lane >> 4, ln16 = lane & 15;
  int p0 = blockIdx.y * 64;
  int h  = p0 / WW;
  int w0 = p0 - h * WW;
  int col0 = blockIdx.x * 64;

  f32x4 acc[4];
  #pragma unroll
  for (int nb = 0; nb < 4; ++nb)
    #pragma unroll
    for (int r = 0; r < 4; ++r) acc[nb][r] = 0.f;

  int nch = (IC + 31) / 32;
  for (int c = 0; c < nch; ++c) {
    int k0 = c * 32;
    // stage packed weights: contiguous coalesced copy (46080 B)
    {
      const h8* src = (const h8*)(Wp + (size_t)(blockIdx.x * nch + c) * PKCHUNK);
      h8* dst = (h8*)wsm;
      #pragma unroll 3
      for (int idx = tid; idx < PKCHUNK/8; idx += 256) dst[idx] = src[idx];
    }
    // stage halo: 3 rows x 66 px x 4 k-segments (float4 fast path)
    for (int idx = tid; idx < 3*66*4; idx += 256) {
      int r    = idx / (66*4);
      int rem  = idx - r*(66*4);
      int px   = rem >> 2;
      int ks   = (rem & 3) * 8;
      int gh = h - 1 + r, gw = w0 - 1 + px;
      h8 hv;
      #pragma unroll
      for (int j = 0; j < 8; ++j) hv[j] = (_Float16)0.f;
      if ((unsigned)gh < (unsigned)HH && (unsigned)gw < (unsigned)WW) {
        const float* sp = X + (size_t)(gh*WW + gw) * IC + k0 + ks;
        if (k0 + ks + 8 <= IC) {
          float4 q0 = *(const float4*)sp;
          float4 q1 = *(const float4*)(sp + 4);
          float v[8] = {q0.x,q0.y,q0.z,q0.w,q1.x,q1.y,q1.z,q1.w};
          if (scale) {
            #pragma unroll
            for (int j = 0; j < 8; ++j) v[j] *= scale[k0 + ks + j];
          }
          #pragma unroll
          for (int j = 0; j < 8; ++j) hv[j] = (_Float16)v[j];
        } else {
          #pragma unroll
          for (int j = 0; j < 8; ++j) {
            int kk = k0 + ks + j;
            if (kk < IC) {
              float v = sp[j];
              if (scale) v *= scale[kk];
              hv[j] = (_Float16)v;
            }
          }
        }
      }
      *(h8*)&hs[r][px][ks] = hv;
    }
    __syncthreads();
    #pragma unroll
    for (int tap = 0; tap < 9; ++tap) {
      int dyy = tap / 3, dxt = tap % 3;
      h8 af = *(const h8*)&hs[dyy][wave*16 + ln16 + dxt][quad*8];
      #pragma unroll
      for (int nb = 0; nb < 4; ++nb) {
        h8 bf = *(const h8*)&wsm[(tap*64 + nb*16 + ln16)*40 + quad*8];
        acc[nb] = __builtin_amdgcn_mfma_f32_16x16x32_f16(af, bf, acc[nb], 0, 0, 0);
      }
    }
    __syncthreads();
  }

  #pragma unroll
  for (int r = 0; r < 4; ++r) {
    int p = p0 + wave*16 + quad*4 + r;
    #pragma unroll
    for (int nb = 0; nb < 4; ++nb) {
      int oc = col0 + nb*16 + ln16;
      if (oc < OC) {
        float v = acc[nb][r] + bias[oc];
        if (RES) v += RES[(size_t)p * OC + oc];
        OUT[(size_t)p * OC + oc] = v;
      }
    }
  }
}

// ---------------------------------------------------------------------------
// Window MSA: one block per (window, head). 256 threads = 256 queries.
// ---------------------------------------------------------------------------
__global__ __launch_bounds__(256) void win_attn_kernel(
    const float* __restrict__ QKV, const float* __restrict__ relb,
    float* __restrict__ OUT, int shift)
{
  __shared__ float ks[NTW * 32];
  __shared__ float vs[NTW * 32];
  __shared__ float rb[961];
  __shared__ unsigned char rg[NTW];
  int b = blockIdx.x;
  int w = b / HEADS, hd = b - (b / HEADS) * HEADS;
  int t = threadIdx.x;
  const float* base = QKV + (size_t)(w * NTW) * 540;

  float q[HD], acc[HD];
  #pragma unroll
  for (int c = 0; c < HD; ++c) {
    q[c] = base[(size_t)t * 540 + hd * HD + c];
    ks[t * 32 + c] = base[(size_t)t * 540 + 180 + hd * HD + c];
    vs[t * 32 + c] = base[(size_t)t * 540 + 360 + hd * HD + c];
    acc[c] = 0.f;
  }
  for (int i = t; i < 961; i += 256) rb[i] = relb[i * HEADS + hd];

  int myreg = 0;
  if (shift > 0) {
    int wh = w / NWW, ww = w - wh * NWW;
    int rh = wh * WS + (t >> 4);
    int rw = ww * WS + (t & 15);
    int regh = (rh < HH - WS) ? 0 : (rh < HH - 8 ? 1 : 2);
    int regw = (rw < WW - WS) ? 0 : (rw < WW - 8 ? 1 : 2);
    myreg = regh * 3 + regw;
    rg[t] = (unsigned char)myreg;
  }
  __syncthreads();

  const float scl = 0.18257418583505536f;
  float mmax = -1e30f, l = 0.f;
  int qi = t >> 4, qj = t & 15;

  for (int ki = 0; ki < NTW; ++ki) {
    const float* kr = &ks[ki * 32];
    float s = 0.f;
    #pragma unroll
    for (int c = 0; c < HD; ++c) s += q[c] * kr[c];
    s *= scl;
    int kii = ki >> 4, kjj = ki & 15;
    s += rb[(qi - kii + 15) * 31 + (qj - kjj + 15)];
    if (shift > 0 && rg[ki] != (unsigned char)myreg) s -= 100.f;
    float nm   = fmaxf(mmax, s);
    float corr = __expf(mmax - nm);
    float p    = __expf(s - nm);
    l = l * corr + p;
    const float* vr = &vs[ki * 32];
    #pragma unroll
    for (int c = 0; c < HD; ++c) acc[c] = acc[c] * corr + p * vr[c];
    mmax = nm;
  }
  float inv = 1.f / l;
  float* o = OUT + (size_t)(w * NTW + t) * C + hd * HD;
  #pragma unroll
  for (int c = 0; c < HD; ++c) o[c] = acc[c] * inv;
}

// ---------------------------------------------------------------------------
// OCAB attention: one block per (window, head).
// ---------------------------------------------------------------------------
__global__ __launch_bounds__(256) void ocab_attn_kernel(
    const float* __restrict__ Q, const float* __restrict__ KV,
    float* __restrict__ OUT)
{
  constexpr int CH = 144;
  __shared__ float ks[CH * 32];
  __shared__ float vs[CH * 32];
  int b = blockIdx.x;
  int w = b / HEADS, hd = b - (b / HEADS) * HEADS;
  int t = threadIdx.x;
  float q[HD], acc[HD];
  const float* qr = Q + (size_t)(w * NTW + t) * C + hd * HD;
  #pragma unroll
  for (int c = 0; c < HD; ++c) { q[c] = qr[c]; acc[c] = 0.f; }
  float mmax = -1e30f, l = 0.f;
  const float scl = 0.18257418583505536f;

  for (int ch = 0; ch < NKV / CH; ++ch) {
    __syncthreads();
    for (int idx = t; idx < CH * HD; idx += 256) {
      int row = idx / HD, c = idx - row * HD;
      const float* kvrow = KV + (size_t)(w * NKV + ch * CH + row) * 360 + hd * HD;
      ks[row * 32 + c] = kvrow[c];
      vs[row * 32 + c] = kvrow[180 + c];
    }
    __syncthreads();
    for (int kk = 0; kk < CH; ++kk) {
      const float* kr = &ks[kk * 32];
      float s = 0.f;
      #pragma unroll
      for (int c = 0; c < HD; ++c) s += q[c] * kr[c];
      s *= scl;
      float nm   = fmaxf(mmax, s);
      float corr = __expf(mmax - nm);
      float p    = __expf(s - nm);
      l = l * corr + p;
      const float* vr = &vs[kk * 32];
      #pragma unroll
      for (int c = 0; c < HD; ++c) acc[c] = acc[c] * corr + p * vr[c];
      mmax = nm;
    }
  }
  float inv = 1.f / l;
  float* o = OUT + (size_t)(w * NTW + t) * C + hd * HD;
  #pragma unroll
  for (int c = 0; c < HD; ++c) o[c] = acc[c] * inv;
}

// ---------------------------------------------------------------------------
__global__ __launch_bounds__(256) void colmean_kernel(
    const float* __restrict__ COMP, float* __restrict__ S)
{
  int c = blockIdx.x;
  float sum = 0.f;
  for (int p = threadIdx.x; p < NT; p += 256)
    sum += COMP[(size_t)p * CCH + c];
  #pragma unroll
  for (int off = 32; off > 0; off >>= 1) sum += __shfl_down(sum, off);
  __shared__ float red[4];
  if ((threadIdx.x & 63) == 0) red[threadIdx.x >> 6] = sum;
  __syncthreads();
  if (threadIdx.x == 0)
    S[c] = (red[0] + red[1] + red[2] + red[3]) * (1.f / NT);
}

__global__ __launch_bounds__(64) void se_kernel(
    const float* __restrict__ S, const float* __restrict__ w1,
    const float* __restrict__ b1, const float* __restrict__ w2,
    const float* __restrict__ b2, float* __restrict__ G)
{
  __shared__ float hid[CSE];
  int t = threadIdx.x;
  if (t < CSE) {
    float a = b1[t];
    for (int c = 0; c < CCH; ++c) a += S[c] * w1[c * CSE + t];
    hid[t] = fmaxf(a, 0.f);
  }
  __syncthreads();
  if (t < CCH) {
    float a = b2[t];
    #pragma unroll
    for (int j = 0; j < CSE; ++j) a += hid[j] * w2[j * CCH + t];
    G[t] = 1.f / (1.f + __expf(-a));
  }
}

// ---------------------------------------------------------------------------

extern "C" void kernel_launch(void* const* d_in, const int* in_sizes, int n_in,
                              void* d_out, int out_size, void* d_ws, size_t ws_size,
                              hipStream_t stream) {
  const float* x_in   = (const float*)d_in[0];
  const float* n1w    = (const float*)d_in[1];
  const float* n1b    = (const float*)d_in[2];
  const float* qkvw   = (const float*)d_in[3];
  const float* qkvb   = (const float*)d_in[4];
  const float* relb   = (const float*)d_in[5];
  const float* projw  = (const float*)d_in[6];
  const float* projb  = (const float*)d_in[7];
  const float* ccw    = (const float*)d_in[8];
  const float* ccb    = (const float*)d_in[9];
  const float* ca1w   = (const float*)d_in[10];
  const float* ca1b   = (const float*)d_in[11];
  const float* ca2w   = (const float*)d_in[12];
  const float* ca2b   = (const float*)d_in[13];
  const float* cew    = (const float*)d_in[14];
  const float* ceb    = (const float*)d_in[15];
  const float* n2w    = (const float*)d_in[16];
  const float* n2b    = (const float*)d_in[17];
  const float* m1w    = (const float*)d_in[18];
  const float* m1b    = (const float*)d_in[19];
  const float* m2w    = (const float*)d_in[20];
  const float* m2b    = (const float*)d_in[21];
  const float* onw    = (const float*)d_in[22];
  const float* onb    = (const float*)d_in[23];
  const float* oqw    = (const float*)d_in[24];
  const float* oqb    = (const float*)d_in[25];
  const float* okvw   = (const float*)d_in[26];
  const float* okvb   = (const float*)d_in[27];
  const float* opw    = (const float*)d_in[28];
  const float* opb    = (const float*)d_in[29];
  const float* convw  = (const float*)d_in[30];
  const float* convb  = (const float*)d_in[31];

  float* ws   = (float*)d_ws;
  float* X    = ws + OFF_X;
  float* A    = ws + OFF_A;
  float* B    = ws + OFF_B;
  float* COMP = ws + OFF_COMP;
  float* S    = ws + OFF_S;
  float* G    = ws + OFF_G;
  float* QKV  = ws + OFF_QKV;
  _Float16* PKCC  = (_Float16*)(ws + OFF_PKCC);   // [6][1*6*PKCHUNK]
  _Float16* PKCE  = (_Float16*)(ws + OFF_PKCE);   // [6][3*2*PKCHUNK]
  _Float16* PKFIN = PKCC;                         // reused after OCAB attn

  (void)hipMemcpyAsync(X, x_in, (size_t)NT * C * sizeof(float),
                       hipMemcpyDeviceToDevice, stream);

  // ---- pack conv weights (cc: 180->60, ce: 60->180) ----
  constexpr int CCTOT = 1*6*PKCHUNK;   // 138240
  constexpr int CETOT = 3*2*PKCHUNK;   // 138240
  for (int i = 0; i < DEPTH; ++i) {
    pack_convw<<<(CCTOT+255)/256, 256, 0, stream>>>(
        ccw + (size_t)i*CCH*C*9, PKCC + (size_t)i*CCTOT, C, CCH, 6, CCTOT);
    pack_convw<<<(CETOT+255)/256, 256, 0, stream>>>(
        cew + (size_t)i*C*CCH*9, PKCE + (size_t)i*CETOT, CCH, C, 2, CETOT);
  }

  const int MB = NT / 64;  // 576 row-blocks

  for (int i = 0; i < DEPTH; ++i) {
    int shift = (i % 2 == 0) ? 0 : WS / 2;
    ln_kernel<<<NT, 64, 0, stream>>>(X, n1w + i*C, n1b + i*C, A, 1, shift);
    gemm_mfma<<<dim3(9, MB), 256, 0, stream>>>(
        A, qkvw + (size_t)i*C*3*C, qkvb + (size_t)i*3*C, QKV, nullptr,
        NT, 3*C, C, 0, 0, 0, 0);
    win_attn_kernel<<<NWIN*HEADS, 256, 0, stream>>>(
        QKV, relb + (size_t)i*961*HEADS, A, shift);
    gemm_mfma<<<dim3(3, MB), 256, 0, stream>>>(
        A, projw + (size_t)i*C*C, projb + (size_t)i*C, X, X,
        NT, C, C, 0, 1, 2, shift);
    conv9_mfma<<<dim3(1, MB), 256, 0, stream>>>(
        X, PKCC + (size_t)i*CCTOT, ccb + (size_t)i*CCH,
        nullptr, nullptr, COMP, C, CCH);
    colmean_kernel<<<CCH, 256, 0, stream>>>(COMP, S);
    se_kernel<<<1, 64, 0, stream>>>(
        S, ca1w + (size_t)i*CCH*CSE, ca1b + (size_t)i*CSE,
        ca2w + (size_t)i*CSE*CCH, ca2b + (size_t)i*CCH, G);
    conv9_mfma<<<dim3(3, MB), 256, 0, stream>>>(
        COMP, PKCE + (size_t)i*CETOT, ceb + (size_t)i*C,
        G, X, X, CCH, C);
    ln_kernel<<<NT, 64, 0, stream>>>(X, n2w + i*C, n2b + i*C, A, 0, 0);
    gemm_mfma<<<dim3(6, MB), 256, 0, stream>>>(
        A, m1w + (size_t)i*C*HID, m1b + (size_t)i*HID, QKV, nullptr,
        NT, HID, C, 0, 0, 1, 0);
    gemm_mfma<<<dim3(3, MB), 256, 0, stream>>>(
        QKV, m2w + (size_t)i*HID*C, m2b + (size_t)i*C, X, X,
        NT, C, HID, 0, 0, 2, 0);
  }

  // ---- OCAB ----
  ln_kernel<<<NT, 64, 0, stream>>>(X, onw, onb, A, 1, 0);
  gemm_mfma<<<dim3(3, MB), 256, 0, stream>>>(
      A, oqw, oqb, B, nullptr, NT, C, C, 0, 0, 0, 0);
  gemm_mfma<<<dim3(6, NWIN*NKV/64), 256, 0, stream>>>(
      A, okvw, okvb, QKV, nullptr, NWIN*NKV, 2*C, C, 1, 0, 0, 0);
  ocab_attn_kernel<<<NWIN*HEADS, 256, 0, stream>>>(B, QKV, A);
  // pack final conv weights (KV region is dead now)
  constexpr int FTOT = 3*6*PKCHUNK;    // 414720
  pack_convw<<<(FTOT+255)/256, 256, 0, stream>>>(
      convw, PKFIN, C, C, 6, FTOT);
  gemm_mfma<<<dim3(3, MB), 256, 0, stream>>>(
      A, opw, opb, X, X, NT, C, C, 0, 1, 2, 0);

  // ---- final conv + global shortcut -> d_out ----
  conv9_mfma<<<dim3(3, MB), 256, 0, stream>>>(
      X, PKFIN, convb, nullptr, x_in, (float*)d_out, C, C);
}

// Round 5
// 4228.597 us; speedup vs baseline: 2.2048x; 1.2826x over previous
//
#include <hip/hip_runtime.h>
#include <math.h>

// ---------------------------------------------------------------------------
// HAT block (HAB x6 + OCAB + conv) — fp32 I/O, f16 MFMA GEMM/conv/attention.
// Attention: S^T = K*Q^T (16x16x32), P feeds PV (16x16x16) directly from
// C-layout (CDNA S^T trick). Conv weights pre-packed to the LDS image.
// ---------------------------------------------------------------------------

#define DEV __device__ __forceinline__

constexpr int HH   = 192;
constexpr int WW   = 192;
constexpr int NT   = HH * WW;     // 36864 tokens
constexpr int C    = 180;
constexpr int HEADS= 6;
constexpr int HD   = 30;
constexpr int WS   = 16;
constexpr int NWW  = WW / WS;     // 12
constexpr int NWIN = (HH/WS)*(WW/WS); // 144
constexpr int NTW  = WS*WS;       // 256
constexpr int OWS  = 24;
constexpr int NKV  = OWS*OWS;     // 576
constexpr int CCH  = 60;
constexpr int CSE  = 6;
constexpr int HID  = 360;
constexpr int DEPTH= 6;

typedef _Float16 h8   __attribute__((ext_vector_type(8)));
typedef _Float16 h4   __attribute__((ext_vector_type(4)));
typedef float    f32x4 __attribute__((ext_vector_type(4)));

// packed conv-weight chunk image: [tap][oc 0..63][k 0..39] halfs
constexpr int PKCHUNK = 9 * 64 * 40;   // 23040 halfs per (col-block, k-chunk)

// workspace offsets (in floats)
constexpr size_t OFF_X    = 0;
constexpr size_t OFF_A    = OFF_X    + (size_t)NT*C;
constexpr size_t OFF_B    = OFF_A    + (size_t)NT*C;
constexpr size_t OFF_COMP = OFF_B    + (size_t)NT*C;
constexpr size_t OFF_S    = OFF_COMP + (size_t)NT*CCH;
constexpr size_t OFF_G    = OFF_S    + 64;
constexpr size_t OFF_QKV  = OFF_G    + 64;      // QKV (19.9M f) / OCAB KV (29.9M f)
constexpr size_t OFF_PKCC = OFF_QKV + (size_t)NT*540;
constexpr size_t OFF_PKCE = OFF_PKCC + (6*6*PKCHUNK)/2;

DEV int win_to_nat(int r, int shift) {
  int w   = r >> 8;
  int pos = r & 255;
  int wh = w / NWW, ww = w - wh*NWW;
  int rh = wh*WS + (pos >> 4);
  int rw = ww*WS + (pos & 15);
  int sh = rh + shift; if (sh >= HH) sh -= HH;
  int sw = rw + shift; if (sw >= WW) sw -= WW;
  return sh*WW + sw;
}

DEV int ocab_src_row(int gr) {
  int w = gr / NKV;
  int t = gr - w*NKV;
  int wh = w / NWW, ww = w - wh*NWW;
  int i = t / OWS, j = t - i*OWS;
  int gh = wh*WS - 4 + i;
  int gw = ww*WS - 4 + j;
  if ((unsigned)gh >= (unsigned)HH || (unsigned)gw >= (unsigned)WW) return -1;
  return (((gh >> 4)*NWW + (gw >> 4)) << 8) + ((gh & 15) << 4) + (gw & 15);
}

DEV float gelu_exact(float v) {
  return 0.5f * v * (1.0f + erff(v * 0.70710678118654752f));
}

// load 30 contiguous fp32 (8B-aligned) -> 32 f16 (scaled), zero-padded
DEV void row30_f16(_Float16* dst, const float* src, float sc) {
  float v[30];
  #pragma unroll
  for (int j = 0; j < 30; j += 2) *(float2*)&v[j] = *(const float2*)(src + j);
  #pragma unroll
  for (int j = 0; j < 30; ++j) dst[j] = (_Float16)(v[j] * sc);
  dst[30] = (_Float16)0.f; dst[31] = (_Float16)0.f;
}

// ---------------------------------------------------------------------------
// Conv weight pack: Wc (OC,IC,3,3) fp32 -> Wp f16 [(cb*nch+ch)][tap][oc64][k40]
// ---------------------------------------------------------------------------
__global__ __launch_bounds__(256) void pack_convw(
    const float* __restrict__ Wc, _Float16* __restrict__ Wp,
    int IC, int OC, int nch, int total)
{
  int idx = blockIdx.x * 256 + threadIdx.x;
  if (idx >= total) return;
  int kk = idx % 40;
  int r  = idx / 40;
  int oc = r & 63; r >>= 6;
  int tap = r % 9; r /= 9;
  int ch = r % nch; int cb = r / nch;
  float v = 0.f;
  int goc = cb*64 + oc, gk = ch*32 + kk;
  if (kk < 32 && goc < OC && gk < IC)
    v = Wc[((size_t)goc * IC + gk) * 9 + tap];
  Wp[idx] = (_Float16)v;
}

// ---------------------------------------------------------------------------
// LayerNorm (+ optional window partition with roll). grid = NT blocks x 64.
// ---------------------------------------------------------------------------
__global__ __launch_bounds__(64) void ln_kernel(
    const float* __restrict__ X, const float* __restrict__ gw,
    const float* __restrict__ gb, float* __restrict__ OUT,
    int mode, int shift)
{
  int r = blockIdx.x;
  int s = (mode == 1) ? win_to_nat(r, shift) : r;
  int lane = threadIdx.x;
  const float* xr = X + (size_t)s * C;
  float v0 = xr[lane];
  float v1 = xr[lane + 64];
  float v2 = (lane < C - 128) ? xr[lane + 128] : 0.f;
  float sum = v0 + v1 + v2;
  float sq  = v0*v0 + v1*v1 + v2*v2;
  #pragma unroll
  for (int off = 32; off > 0; off >>= 1) {
    sum += __shfl_down(sum, off);
    sq  += __shfl_down(sq,  off);
  }
  sum = __shfl(sum, 0);
  sq  = __shfl(sq,  0);
  float mu  = sum * (1.f / C);
  float var = sq * (1.f / C) - mu * mu;
  float inv = rsqrtf(var + 1e-5f);
  float* orow = OUT + (size_t)r * C;
  orow[lane]      = (v0 - mu) * inv * gw[lane]      + gb[lane];
  orow[lane + 64] = (v1 - mu) * inv * gw[lane + 64] + gb[lane + 64];
  if (lane < C - 128)
    orow[lane + 128] = (v2 - mu) * inv * gw[lane + 128] + gb[lane + 128];
}

// ---------------------------------------------------------------------------
// MFMA f16 GEMM: OUT = X(M,K) @ W(K,N) + bias. 64x64x32 tile, 4 waves.
// ---------------------------------------------------------------------------
__global__ __launch_bounds__(256) void gemm_mfma(
    const float* __restrict__ X, const float* __restrict__ Wm,
    const float* __restrict__ bias, float* __restrict__ OUT,
    const float* __restrict__ RES,
    int M, int N, int K, int amap, int emap, int epi, int shift)
{
  __shared__ _Float16 As[64][40];
  __shared__ _Float16 Bs[64][40];
  int tid  = threadIdx.x;
  int lane = tid & 63, wave = tid >> 6;
  int quad = lane >> 4, ln16 = lane & 15;
  int row0 = blockIdx.y * 64;
  int col0 = blockIdx.x * 64;

  f32x4 acc[4];
  #pragma unroll
  for (int nb = 0; nb < 4; ++nb)
    #pragma unroll
    for (int r = 0; r < 4; ++r) acc[nb][r] = 0.f;

  int ar = tid >> 2;
  int ak = (tid & 3) * 8;
  int gr = row0 + ar;
  int sr = (amap == 1) ? ocab_src_row(gr) : gr;
  const float* xrow = (sr >= 0) ? X + (size_t)sr * K : nullptr;
  int bn = tid & 63, bko = (tid >> 6) * 8;
  int gc = col0 + bn;

  int nch = (K + 31) / 32;
  for (int c = 0; c < nch; ++c) {
    int k0 = c * 32;
    {
      h8 av;
      int kb = k0 + ak;
      if (xrow && kb + 8 <= K) {
        float4 p0 = *(const float4*)(xrow + kb);
        float4 p1 = *(const float4*)(xrow + kb + 4);
        av[0]=(_Float16)p0.x; av[1]=(_Float16)p0.y; av[2]=(_Float16)p0.z; av[3]=(_Float16)p0.w;
        av[4]=(_Float16)p1.x; av[5]=(_Float16)p1.y; av[6]=(_Float16)p1.z; av[7]=(_Float16)p1.w;
      } else {
        #pragma unroll
        for (int j = 0; j < 8; ++j) {
          float v = (xrow && kb + j < K) ? xrow[kb + j] : 0.f;
          av[j] = (_Float16)v;
        }
      }
      *(h8*)&As[ar][ak] = av;
    }
    {
      h8 bv;
      #pragma unroll
      for (int j = 0; j < 8; ++j) {
        int kk = k0 + bko + j;
        float v = (kk < K && gc < N) ? Wm[(size_t)kk * N + gc] : 0.f;
        bv[j] = (_Float16)v;
      }
      *(h8*)&Bs[bn][bko] = bv;
    }
    __syncthreads();
    h8 af = *(const h8*)&As[wave*16 + ln16][quad*8];
    #pragma unroll
    for (int nb = 0; nb < 4; ++nb) {
      h8 bf = *(const h8*)&Bs[nb*16 + ln16][quad*8];
      acc[nb] = __builtin_amdgcn_mfma_f32_16x16x32_f16(af, bf, acc[nb], 0, 0, 0);
    }
    __syncthreads();
  }

  #pragma unroll
  for (int r = 0; r < 4; ++r) {
    int m   = row0 + wave*16 + quad*4 + r;
    int dst = (emap == 1) ? win_to_nat(m, shift) : m;
    #pragma unroll
    for (int nb = 0; nb < 4; ++nb) {
      int n = col0 + nb*16 + ln16;
      if (n < N) {
        float v = acc[nb][r] + bias[n];
        if (epi == 1) v = gelu_exact(v);
        if (epi == 2) v += RES[(size_t)dst * N + n];
        OUT[(size_t)dst * N + n] = v;
      }
    }
  }
}

// ---------------------------------------------------------------------------
// MFMA f16 3x3 conv, channels-last, packed weights.
// ---------------------------------------------------------------------------
__global__ __launch_bounds__(256) void conv9_mfma(
    const float* __restrict__ X, const _Float16* __restrict__ Wp,
    const float* __restrict__ bias, const float* __restrict__ scale,
    const float* __restrict__ RES, float* __restrict__ OUT,
    int IC, int OC)
{
  __shared__ _Float16 hs[3][66][40];
  __shared__ _Float16 wsm[PKCHUNK];
  int tid  = threadIdx.x;
  int lane = tid & 63, wave = tid >> 6;
  int quad = lane >> 4, ln16 = lane & 15;
  int p0 = blockIdx.y * 64;
  int h  = p0 / WW;
  int w0 = p0 - h * WW;
  int col0 = blockIdx.x * 64;

  f32x4 acc[4];
  #pragma unroll
  for (int nb = 0; nb < 4; ++nb)
    #pragma unroll
    for (int r = 0; r < 4; ++r) acc[nb][r] = 0.f;

  int nch = (IC + 31) / 32;
  for (int c = 0; c < nch; ++c) {
    int k0 = c * 32;
    {
      const h8* src = (const h8*)(Wp + (size_t)(blockIdx.x * nch + c) * PKCHUNK);
      h8* dst = (h8*)wsm;
      #pragma unroll 3
      for (int idx = tid; idx < PKCHUNK/8; idx += 256) dst[idx] = src[idx];
    }
    for (int idx = tid; idx < 3*66*4; idx += 256) {
      int r    = idx / (66*4);
      int rem  = idx - r*(66*4);
      int px   = rem >> 2;
      int ks   = (rem & 3) * 8;
      int gh = h - 1 + r, gw = w0 - 1 + px;
      h8 hv;
      #pragma unroll
      for (int j = 0; j < 8; ++j) hv[j] = (_Float16)0.f;
      if ((unsigned)gh < (unsigned)HH && (unsigned)gw < (unsigned)WW) {
        const float* sp = X + (size_t)(gh*WW + gw) * IC + k0 + ks;
        if (k0 + ks + 8 <= IC) {
          float4 q0 = *(const float4*)sp;
          float4 q1 = *(const float4*)(sp + 4);
          float v[8] = {q0.x,q0.y,q0.z,q0.w,q1.x,q1.y,q1.z,q1.w};
          if (scale) {
            #pragma unroll
            for (int j = 0; j < 8; ++j) v[j] *= scale[k0 + ks + j];
          }
          #pragma unroll
          for (int j = 0; j < 8; ++j) hv[j] = (_Float16)v[j];
        } else {
          #pragma unroll
          for (int j = 0; j < 8; ++j) {
            int kk = k0 + ks + j;
            if (kk < IC) {
              float v = sp[j];
              if (scale) v *= scale[kk];
              hv[j] = (_Float16)v;
            }
          }
        }
      }
      *(h8*)&hs[r][px][ks] = hv;
    }
    __syncthreads();
    #pragma unroll
    for (int tap = 0; tap < 9; ++tap) {
      int dyy = tap / 3, dxt = tap % 3;
      h8 af = *(const h8*)&hs[dyy][wave*16 + ln16 + dxt][quad*8];
      #pragma unroll
      for (int nb = 0; nb < 4; ++nb) {
        h8 bf = *(const h8*)&wsm[(tap*64 + nb*16 + ln16)*40 + quad*8];
        acc[nb] = __builtin_amdgcn_mfma_f32_16x16x32_f16(af, bf, acc[nb], 0, 0, 0);
      }
    }
    __syncthreads();
  }

  #pragma unroll
  for (int r = 0; r < 4; ++r) {
    int p = p0 + wave*16 + quad*4 + r;
    #pragma unroll
    for (int nb = 0; nb < 4; ++nb) {
      int oc = col0 + nb*16 + ln16;
      if (oc < OC) {
        float v = acc[nb][r] + bias[oc];
        if (RES) v += RES[(size_t)p * OC + oc];
        OUT[(size_t)p * OC + oc] = v;
      }
    }
  }
}

// ---------------------------------------------------------------------------
// MFMA window attention. One block per (window, head), 4 waves x 64 queries.
// S^T = K*Q^T (16x16x32), online softmax in C-layout, PV via 16x16x16 with
// P converted in-register from the S^T C-tiles. Vt staged transposed [d][key].
// ---------------------------------------------------------------------------
__global__ __launch_bounds__(256) void win_attn_mfma(
    const float* __restrict__ QKV, const float* __restrict__ relb,
    float* __restrict__ OUT, int shift)
{
  __shared__ _Float16 Kf[256][40];
  __shared__ _Float16 Vt[32][268];
  __shared__ _Float16 rbs[962];
  __shared__ unsigned char rg[256];
  int b = blockIdx.x;
  int w = b / HEADS, hd = b - (b / HEADS)*HEADS;
  int tid = threadIdx.x, lane = tid & 63, wave = tid >> 6;
  int quad = lane >> 4, ln16 = lane & 15;
  const float* base = QKV + (size_t)(w*NTW)*540;
  const float scl = 0.18257418583505536f;  // 1/sqrt(30)

  // stage K rows (f16, pad 30->32)
  row30_f16(&Kf[tid][0], base + (size_t)tid*540 + 180 + hd*HD, 1.f);
  // stage V transposed [d][key]
  #pragma unroll
  for (int rr = 0; rr < 4; ++rr) {
    int task = rr*256 + tid;
    int kg = task >> 5, d = task & 31;
    h8 hv;
    #pragma unroll
    for (int j = 0; j < 8; ++j) {
      int key = kg*8 + j;
      float v = (d < HD) ? base[(size_t)key*540 + 360 + hd*HD + d] : 0.f;
      hv[j] = (_Float16)v;
    }
    *(h8*)&Vt[d][kg*8] = hv;
  }
  for (int i = tid; i < 961; i += 256) rbs[i] = (_Float16)relb[i*HEADS + hd];
  if (shift > 0) {
    int wh = w / NWW, ww = w - wh*NWW;
    int rh = wh*WS + (tid >> 4), rw = ww*WS + (tid & 15);
    int regh = (rh < HH - WS) ? 0 : (rh < HH - 8 ? 1 : 2);
    int regw = (rw < WW - WS) ? 0 : (rw < WW - 8 ? 1 : 2);
    rg[tid] = (unsigned char)(regh*3 + regw);
  }

  // Q B-frags from global (pre-scaled): B[n=q=ln16][k=d=quad*8+j]
  h8 bq[4];
  #pragma unroll
  for (int qi = 0; qi < 4; ++qi) {
    int q = wave*64 + qi*16 + ln16;
    const float* qr = base + (size_t)q*540 + hd*HD + quad*8;
    if (quad < 3) {
      float vv[8];
      #pragma unroll
      for (int j = 0; j < 8; j += 2) *(float2*)&vv[j] = *(const float2*)(qr + j);
      #pragma unroll
      for (int j = 0; j < 8; ++j) bq[qi][j] = (_Float16)(vv[j]*scl);
    } else {
      float vv[6];
      #pragma unroll
      for (int j = 0; j < 6; j += 2) *(float2*)&vv[j] = *(const float2*)(qr + j);
      #pragma unroll
      for (int j = 0; j < 6; ++j) bq[qi][j] = (_Float16)(vv[j]*scl);
      bq[qi][6] = (_Float16)0.f; bq[qi][7] = (_Float16)0.f;
    }
  }
  __syncthreads();

  float mrun[4], lrun[4];
  f32x4 accO[4][2];
  #pragma unroll
  for (int qi = 0; qi < 4; ++qi) {
    mrun[qi] = -1e30f; lrun[qi] = 0.f;
    #pragma unroll
    for (int r = 0; r < 4; ++r) { accO[qi][0][r] = 0.f; accO[qi][1][r] = 0.f; }
  }
  int rgq[4] = {0,0,0,0};
  if (shift > 0) {
    #pragma unroll
    for (int qi = 0; qi < 4; ++qi) rgq[qi] = rg[wave*64 + qi*16 + ln16];
  }
  const f32x4 zero4 = {0.f,0.f,0.f,0.f};

  for (int kb = 0; kb < 4; ++kb) {
    f32x4 st[4][4];
    #pragma unroll
    for (int kt = 0; kt < 4; ++kt) {
      h8 ak = *(const h8*)&Kf[kb*64 + kt*16 + ln16][quad*8];
      #pragma unroll
      for (int qi = 0; qi < 4; ++qi)
        st[kt][qi] = __builtin_amdgcn_mfma_f32_16x16x32_f16(ak, bq[qi], zero4, 0, 0, 0);
    }
    #pragma unroll
    for (int qi = 0; qi < 4; ++qi) {
      int q = wave*64 + qi*16 + ln16;
      int qrr = q >> 4, qcc = q & 15;
      float bmax = -1e30f;
      #pragma unroll
      for (int kt = 0; kt < 4; ++kt) {
        int bidx0 = (qrr - (kb*4 + kt) + 15)*31 + qcc + 15 - quad*4;
        #pragma unroll
        for (int r = 0; r < 4; ++r) {
          float s = st[kt][qi][r] + (float)rbs[bidx0 - r];
          if (shift > 0) {
            int key = kb*64 + kt*16 + quad*4 + r;
            if (rg[key] != rgq[qi]) s -= 100.f;
          }
          st[kt][qi][r] = s;
          bmax = fmaxf(bmax, s);
        }
      }
      bmax = fmaxf(bmax, __shfl_xor(bmax, 16));
      bmax = fmaxf(bmax, __shfl_xor(bmax, 32));
      float mnew  = fmaxf(mrun[qi], bmax);
      float alpha = __expf(mrun[qi] - mnew);
      mrun[qi] = mnew;
      float ps = 0.f;
      #pragma unroll
      for (int kt = 0; kt < 4; ++kt)
        #pragma unroll
        for (int r = 0; r < 4; ++r) {
          float p = __expf(st[kt][qi][r] - mnew);
          st[kt][qi][r] = p; ps += p;
        }
      ps += __shfl_xor(ps, 16);
      ps += __shfl_xor(ps, 32);
      lrun[qi] = lrun[qi]*alpha + ps;
      #pragma unroll
      for (int r = 0; r < 4; ++r) {
        float fr = __shfl(alpha, quad*4 + r);
        accO[qi][0][r] *= fr;
        accO[qi][1][r] *= fr;
      }
    }
    #pragma unroll
    for (int kt = 0; kt < 4; ++kt) {
      int kbase = kb*64 + kt*16 + quad*4;
      h4 bv0 = *(const h4*)&Vt[ln16][kbase];
      h4 bv1 = *(const h4*)&Vt[16 + ln16][kbase];
      #pragma unroll
      for (int qi = 0; qi < 4; ++qi) {
        h4 ap;
        #pragma unroll
        for (int j = 0; j < 4; ++j) ap[j] = (_Float16)st[kt][qi][j];
        accO[qi][0] = __builtin_amdgcn_mfma_f32_16x16x16f16(ap, bv0, accO[qi][0], 0, 0, 0);
        accO[qi][1] = __builtin_amdgcn_mfma_f32_16x16x16f16(ap, bv1, accO[qi][1], 0, 0, 0);
      }
    }
  }

  #pragma unroll
  for (int qi = 0; qi < 4; ++qi) {
    float linv = 1.f / lrun[qi];
    #pragma unroll
    for (int r = 0; r < 4; ++r) {
      float fr = __shfl(linv, quad*4 + r);
      int q = wave*64 + qi*16 + quad*4 + r;
      float* o = OUT + (size_t)(w*NTW + q)*C + hd*HD;
      o[ln16] = accO[qi][0][r] * fr;
      if (ln16 < HD - 16) o[16 + ln16] = accO[qi][1][r] * fr;
    }
  }
}

// ---------------------------------------------------------------------------
// MFMA OCAB attention. 576 keys in 3 chunks of 192. Same S^T/PV structure,
// no bias/mask. Q from B buffer (window-ordered), KV (144*576, 360) [K|V].
// ---------------------------------------------------------------------------
__global__ __launch_bounds__(256) void ocab_attn_mfma(
    const float* __restrict__ Q, const float* __restrict__ KV,
    float* __restrict__ OUT)
{
  constexpr int CH = 192;
  __shared__ _Float16 Kf[CH][40];
  __shared__ _Float16 Vt[32][204];
  int b = blockIdx.x;
  int w = b / HEADS, hd = b - (b / HEADS)*HEADS;
  int tid = threadIdx.x, lane = tid & 63, wave = tid >> 6;
  int quad = lane >> 4, ln16 = lane & 15;
  const float scl = 0.18257418583505536f;

  h8 bq[4];
  #pragma unroll
  for (int qi = 0; qi < 4; ++qi) {
    int q = wave*64 + qi*16 + ln16;
    const float* qr = Q + (size_t)(w*NTW + q)*C + hd*HD + quad*8;
    if (quad < 3) {
      float vv[8];
      #pragma unroll
      for (int j = 0; j < 8; j += 2) *(float2*)&vv[j] = *(const float2*)(qr + j);
      #pragma unroll
      for (int j = 0; j < 8; ++j) bq[qi][j] = (_Float16)(vv[j]*scl);
    } else {
      float vv[6];
      #pragma unroll
      for (int j = 0; j < 6; j += 2) *(float2*)&vv[j] = *(const float2*)(qr + j);
      #pragma unroll
      for (int j = 0; j < 6; ++j) bq[qi][j] = (_Float16)(vv[j]*scl);
      bq[qi][6] = (_Float16)0.f; bq[qi][7] = (_Float16)0.f;
    }
  }

  float mrun[4], lrun[4];
  f32x4 accO[4][2];
  #pragma unroll
  for (int qi = 0; qi < 4; ++qi) {
    mrun[qi] = -1e30f; lrun[qi] = 0.f;
    #pragma unroll
    for (int r = 0; r < 4; ++r) { accO[qi][0][r] = 0.f; accO[qi][1][r] = 0.f; }
  }
  const f32x4 zero4 = {0.f,0.f,0.f,0.f};

  for (int ch = 0; ch < 3; ++ch) {
    __syncthreads();
    if (tid < CH)
      row30_f16(&Kf[tid][0], KV + (size_t)(w*NKV + ch*CH + tid)*360 + hd*HD, 1.f);
    #pragma unroll
    for (int rr = 0; rr < 3; ++rr) {
      int task = rr*256 + tid;
      int kg = task >> 5, d = task & 31;
      h8 hv;
      #pragma unroll
      for (int j = 0; j < 8; ++j) {
        int key = ch*CH + kg*8 + j;
        float v = (d < HD) ? KV[(size_t)(w*NKV + key)*360 + 180 + hd*HD + d] : 0.f;
        hv[j] = (_Float16)v;
      }
      *(h8*)&Vt[d][kg*8] = hv;
    }
    __syncthreads();

    for (int kb = 0; kb < 3; ++kb) {
      f32x4 st[4][4];
      #pragma unroll
      for (int kt = 0; kt < 4; ++kt) {
        h8 ak = *(const h8*)&Kf[kb*64 + kt*16 + ln16][quad*8];
        #pragma unroll
        for (int qi = 0; qi < 4; ++qi)
          st[kt][qi] = __builtin_amdgcn_mfma_f32_16x16x32_f16(ak, bq[qi], zero4, 0, 0, 0);
      }
      #pragma unroll
      for (int qi = 0; qi < 4; ++qi) {
        float bmax = -1e30f;
        #pragma unroll
        for (int kt = 0; kt < 4; ++kt)
          #pragma unroll
          for (int r = 0; r < 4; ++r) bmax = fmaxf(bmax, st[kt][qi][r]);
        bmax = fmaxf(bmax, __shfl_xor(bmax, 16));
        bmax = fmaxf(bmax, __shfl_xor(bmax, 32));
        float mnew  = fmaxf(mrun[qi], bmax);
        float alpha = __expf(mrun[qi] - mnew);
        mrun[qi] = mnew;
        float ps = 0.f;
        #pragma unroll
        for (int kt = 0; kt < 4; ++kt)
          #pragma unroll
          for (int r = 0; r < 4; ++r) {
            float p = __expf(st[kt][qi][r] - mnew);
            st[kt][qi][r] = p; ps += p;
          }
        ps += __shfl_xor(ps, 16);
        ps += __shfl_xor(ps, 32);
        lrun[qi] = lrun[qi]*alpha + ps;
        #pragma unroll
        for (int r = 0; r < 4; ++r) {
          float fr = __shfl(alpha, quad*4 + r);
          accO[qi][0][r] *= fr;
          accO[qi][1][r] *= fr;
        }
      }
      #pragma unroll
      for (int kt = 0; kt < 4; ++kt) {
        int kbase = kb*64 + kt*16 + quad*4;
        h4 bv0 = *(const h4*)&Vt[ln16][kbase];
        h4 bv1 = *(const h4*)&Vt[16 + ln16][kbase];
        #pragma unroll
        for (int qi = 0; qi < 4; ++qi) {
          h4 ap;
          #pragma unroll
          for (int j = 0; j < 4; ++j) ap[j] = (_Float16)st[kt][qi][j];
          accO[qi][0] = __builtin_amdgcn_mfma_f32_16x16x16f16(ap, bv0, accO[qi][0], 0, 0, 0);
          accO[qi][1] = __builtin_amdgcn_mfma_f32_16x16x16f16(ap, bv1, accO[qi][1], 0, 0, 0);
        }
      }
    }
  }

  #pragma unroll
  for (int qi = 0; qi < 4; ++qi) {
    float linv = 1.f / lrun[qi];
    #pragma unroll
    for (int r = 0; r < 4; ++r) {
      float fr = __shfl(linv, quad*4 + r);
      int q = wave*64 + qi*16 + quad*4 + r;
      float* o = OUT + (size_t)(w*NTW + q)*C + hd*HD;
      o[ln16] = accO[qi][0][r] * fr;
      if (ln16 < HD - 16) o[16 + ln16] = accO[qi][1][r] * fr;
    }
  }
}

// ---------------------------------------------------------------------------
__global__ __launch_bounds__(256) void colmean_kernel(
    const float* __restrict__ COMP, float* __restrict__ S)
{
  int c = blockIdx.x;
  float sum = 0.f;
  for (int p = threadIdx.x; p < NT; p += 256)
    sum += COMP[(size_t)p * CCH + c];
  #pragma unroll
  for (int off = 32; off > 0; off >>= 1) sum += __shfl_down(sum, off);
  __shared__ float red[4];
  if ((threadIdx.x & 63) == 0) red[threadIdx.x >> 6] = sum;
  __syncthreads();
  if (threadIdx.x == 0)
    S[c] = (red[0] + red[1] + red[2] + red[3]) * (1.f / NT);
}

__global__ __launch_bounds__(64) void se_kernel(
    const float* __restrict__ S, const float* __restrict__ w1,
    const float* __restrict__ b1, const float* __restrict__ w2,
    const float* __restrict__ b2, float* __restrict__ G)
{
  __shared__ float hid[CSE];
  int t = threadIdx.x;
  if (t < CSE) {
    float a = b1[t];
    for (int c = 0; c < CCH; ++c) a += S[c] * w1[c * CSE + t];
    hid[t] = fmaxf(a, 0.f);
  }
  __syncthreads();
  if (t < CCH) {
    float a = b2[t];
    #pragma unroll
    for (int j = 0; j < CSE; ++j) a += hid[j] * w2[j * CCH + t];
    G[t] = 1.f / (1.f + __expf(-a));
  }
}

// ---------------------------------------------------------------------------

extern "C" void kernel_launch(void* const* d_in, const int* in_sizes, int n_in,
                              void* d_out, int out_size, void* d_ws, size_t ws_size,
                              hipStream_t stream) {
  const float* x_in   = (const float*)d_in[0];
  const float* n1w    = (const float*)d_in[1];
  const float* n1b    = (const float*)d_in[2];
  const float* qkvw   = (const float*)d_in[3];
  const float* qkvb   = (const float*)d_in[4];
  const float* relb   = (const float*)d_in[5];
  const float* projw  = (const float*)d_in[6];
  const float* projb  = (const float*)d_in[7];
  const float* ccw    = (const float*)d_in[8];
  const float* ccb    = (const float*)d_in[9];
  const float* ca1w   = (const float*)d_in[10];
  const float* ca1b   = (const float*)d_in[11];
  const float* ca2w   = (const float*)d_in[12];
  const float* ca2b   = (const float*)d_in[13];
  const float* cew    = (const float*)d_in[14];
  const float* ceb    = (const float*)d_in[15];
  const float* n2w    = (const float*)d_in[16];
  const float* n2b    = (const float*)d_in[17];
  const float* m1w    = (const float*)d_in[18];
  const float* m1b    = (const float*)d_in[19];
  const float* m2w    = (const float*)d_in[20];
  const float* m2b    = (const float*)d_in[21];
  const float* onw    = (const float*)d_in[22];
  const float* onb    = (const float*)d_in[23];
  const float* oqw    = (const float*)d_in[24];
  const float* oqb    = (const float*)d_in[25];
  const float* okvw   = (const float*)d_in[26];
  const float* okvb   = (const float*)d_in[27];
  const float* opw    = (const float*)d_in[28];
  const float* opb    = (const float*)d_in[29];
  const float* convw  = (const float*)d_in[30];
  const float* convb  = (const float*)d_in[31];

  float* ws   = (float*)d_ws;
  float* X    = ws + OFF_X;
  float* A    = ws + OFF_A;
  float* B    = ws + OFF_B;
  float* COMP = ws + OFF_COMP;
  float* S    = ws + OFF_S;
  float* G    = ws + OFF_G;
  float* QKV  = ws + OFF_QKV;
  _Float16* PKCC  = (_Float16*)(ws + OFF_PKCC);
  _Float16* PKCE  = (_Float16*)(ws + OFF_PKCE);
  _Float16* PKFIN = PKCC;

  (void)hipMemcpyAsync(X, x_in, (size_t)NT * C * sizeof(float),
                       hipMemcpyDeviceToDevice, stream);

  constexpr int CCTOT = 1*6*PKCHUNK;
  constexpr int CETOT = 3*2*PKCHUNK;
  for (int i = 0; i < DEPTH; ++i) {
    pack_convw<<<(CCTOT+255)/256, 256, 0, stream>>>(
        ccw + (size_t)i*CCH*C*9, PKCC + (size_t)i*CCTOT, C, CCH, 6, CCTOT);
    pack_convw<<<(CETOT+255)/256, 256, 0, stream>>>(
        cew + (size_t)i*C*CCH*9, PKCE + (size_t)i*CETOT, CCH, C, 2, CETOT);
  }

  const int MB = NT / 64;

  for (int i = 0; i < DEPTH; ++i) {
    int shift = (i % 2 == 0) ? 0 : WS / 2;
    ln_kernel<<<NT, 64, 0, stream>>>(X, n1w + i*C, n1b + i*C, A, 1, shift);
    gemm_mfma<<<dim3(9, MB), 256, 0, stream>>>(
        A, qkvw + (size_t)i*C*3*C, qkvb + (size_t)i*3*C, QKV, nullptr,
        NT, 3*C, C, 0, 0, 0, 0);
    win_attn_mfma<<<NWIN*HEADS, 256, 0, stream>>>(
        QKV, relb + (size_t)i*961*HEADS, A, shift);
    gemm_mfma<<<dim3(3, MB), 256, 0, stream>>>(
        A, projw + (size_t)i*C*C, projb + (size_t)i*C, X, X,
        NT, C, C, 0, 1, 2, shift);
    conv9_mfma<<<dim3(1, MB), 256, 0, stream>>>(
        X, PKCC + (size_t)i*CCTOT, ccb + (size_t)i*CCH,
        nullptr, nullptr, COMP, C, CCH);
    colmean_kernel<<<CCH, 256, 0, stream>>>(COMP, S);
    se_kernel<<<1, 64, 0, stream>>>(
        S, ca1w + (size_t)i*CCH*CSE, ca1b + (size_t)i*CSE,
        ca2w + (size_t)i*CSE*CCH, ca2b + (size_t)i*CCH, G);
    conv9_mfma<<<dim3(3, MB), 256, 0, stream>>>(
        COMP, PKCE + (size_t)i*CETOT, ceb + (size_t)i*C,
        G, X, X, CCH, C);
    ln_kernel<<<NT, 64, 0, stream>>>(X, n2w + i*C, n2b + i*C, A, 0, 0);
    gemm_mfma<<<dim3(6, MB), 256, 0, stream>>>(
        A, m1w + (size_t)i*C*HID, m1b + (size_t)i*HID, QKV, nullptr,
        NT, HID, C, 0, 0, 1, 0);
    gemm_mfma<<<dim3(3, MB), 256, 0, stream>>>(
        QKV, m2w + (size_t)i*HID*C, m2b + (size_t)i*C, X, X,
        NT, C, HID, 0, 0, 2, 0);
  }

  // ---- OCAB ----
  ln_kernel<<<NT, 64, 0, stream>>>(X, onw, onb, A, 1, 0);
  gemm_mfma<<<dim3(3, MB), 256, 0, stream>>>(
      A, oqw, oqb, B, nullptr, NT, C, C, 0, 0, 0, 0);
  gemm_mfma<<<dim3(6, NWIN*NKV/64), 256, 0, stream>>>(
      A, okvw, okvb, QKV, nullptr, NWIN*NKV, 2*C, C, 1, 0, 0, 0);
  ocab_attn_mfma<<<NWIN*HEADS, 256, 0, stream>>>(B, QKV, A);
  constexpr int FTOT = 3*6*PKCHUNK;
  pack_convw<<<(FTOT+255)/256, 256, 0, stream>>>(
      convw, PKFIN, C, C, 6, FTOT);
  gemm_mfma<<<dim3(3, MB), 256, 0, stream>>>(
      A, opw, opb, X, X, NT, C, C, 0, 1, 2, 0);

  conv9_mfma<<<dim3(3, MB), 256, 0, stream>>>(
      X, PKFIN, convb, nullptr, x_in, (float*)d_out, C, C);
}

// Round 6
// 2829.241 us; speedup vs baseline: 3.2953x; 1.4946x over previous
//
#include <hip/hip_runtime.h>
#include <math.h>

// ---------------------------------------------------------------------------
// HAT block — fp32 residual stream, f16 activations + packed f16 weights,
// MFMA everywhere. Head dims padded 30->32 (zero weights) for aligned frags.
// ---------------------------------------------------------------------------

#define DEV __device__ __forceinline__

constexpr int HH   = 192;
constexpr int WW   = 192;
constexpr int NT   = HH * WW;     // 36864
constexpr int C    = 180;
constexpr int HEADS= 6;
constexpr int HD   = 30;
constexpr int WS   = 16;
constexpr int NWW  = WW / WS;     // 12
constexpr int NWIN = 144;
constexpr int NTW  = 256;
constexpr int OWS  = 24;
constexpr int NKV  = OWS*OWS;     // 576
constexpr int CCH  = 60;
constexpr int CSE  = 6;
constexpr int HID  = 360;
constexpr int DEPTH= 6;

typedef _Float16 h8   __attribute__((ext_vector_type(8)));
typedef _Float16 h4   __attribute__((ext_vector_type(4)));
typedef float    f32x4 __attribute__((ext_vector_type(4)));

constexpr int PKG     = 2560;          // halfs per (cb,ch) gemm pack unit (64x40)
constexpr int PKCHUNK = 9 * 64 * 40;   // conv pack unit (tap,oc64,k40)

// per-layer pack sizes (halfs)
constexpr int QKV_PL = 9*6*PKG;
constexpr int PROJ_PL= 3*6*PKG;
constexpr int M1_PL  = 6*6*PKG;
constexpr int M2_PL  = 3*12*PKG;
constexpr int OQ_PL  = 3*6*PKG;
constexpr int OKV_PL = 6*6*PKG;
constexpr int OP_PL  = 3*6*PKG;
constexpr int CC_PL  = 1*6*PKCHUNK;
constexpr int CE_PL  = 3*2*PKCHUNK;
constexpr int FIN_PL = 3*6*PKCHUNK;

// pack offsets (halfs, from PK base)
constexpr size_t PO_QKV = 0;
constexpr size_t PO_PROJ= PO_QKV + 6ull*QKV_PL;
constexpr size_t PO_M1  = PO_PROJ+ 6ull*PROJ_PL;
constexpr size_t PO_M2  = PO_M1  + 6ull*M1_PL;
constexpr size_t PO_OQ  = PO_M2  + 6ull*M2_PL;
constexpr size_t PO_OKV = PO_OQ  + OQ_PL;
constexpr size_t PO_OP  = PO_OKV + OKV_PL;
constexpr size_t PO_CC  = PO_OP  + OP_PL;
constexpr size_t PO_CE  = PO_CC  + 6ull*CC_PL;
constexpr size_t PO_FIN = PO_CE  + 6ull*CE_PL;
constexpr size_t PK_HALFS = PO_FIN + FIN_PL;   // ~4.47M halfs

// workspace offsets (floats)
constexpr size_t OFF_X    = 0;                          // X fp32 NT*180
constexpr size_t OFF_A    = OFF_X    + (size_t)NT*C;    // A f16 (stride 192)
constexpr size_t OFF_B    = OFF_A    + (size_t)NT*C;    // B f16 (stride 192)
constexpr size_t OFF_COMP = OFF_B    + (size_t)NT*C;    // COMP f16 (stride 64)
constexpr size_t OFF_S    = OFF_COMP + (size_t)NT*CCH;
constexpr size_t OFF_G    = OFF_S    + 64;
constexpr size_t OFF_QKV  = OFF_G    + 64;              // QKV/KV/GELU f16 region
constexpr size_t OFF_PK   = OFF_QKV  + 16000000;        // packed weights (halfs)
constexpr size_t OFF_PB   = OFF_PK   + PK_HALFS/2 + 8;  // packed biases (fp32)
// PB layout: qkvB 6*576 | oqB 192 | okvB 384

DEV int win_to_nat(int r, int shift) {
  int w   = r >> 8;
  int pos = r & 255;
  int wh = w / NWW, ww = w - wh*NWW;
  int rh = wh*WS + (pos >> 4);
  int rw = ww*WS + (pos & 15);
  int sh = rh + shift; if (sh >= HH) sh -= HH;
  int sw = rw + shift; if (sw >= WW) sw -= WW;
  return sh*WW + sw;
}

DEV int ocab_src_row(int gr) {
  int w = gr / NKV;
  int t = gr - w*NKV;
  int wh = w / NWW, ww = w - wh*NWW;
  int i = t / OWS, j = t - i*OWS;
  int gh = wh*WS - 4 + i;
  int gw = ww*WS - 4 + j;
  if ((unsigned)gh >= (unsigned)HH || (unsigned)gw >= (unsigned)WW) return -1;
  return (((gh >> 4)*NWW + (gw >> 4)) << 8) + ((gh & 15) << 4) + (gw & 15);
}

DEV float gelu_exact(float v) {
  return 0.5f * v * (1.0f + erff(v * 0.70710678118654752f));
}

// col remap for padded layouts. returns src col or -1 (zero pad)
DEV int col_remap(int np, int mode) {
  if (mode == 0) return np;                  // identity (guard vs N outside)
  int d = np & 31, hh = (np >> 5) % 6;
  if (d >= 30) return -1;
  if (mode == 1) { int third = np / 192; return third*180 + hh*30 + d; }
  if (mode == 2) { int half  = np / 192; return half *180 + hh*30 + d; }
  return hh*30 + d;                          // mode 3 (q, scaled)
}

// ---------------------------------------------------------------------------
// GEMM weight pack: W (K,N) fp32 -> [layer][cb][ch][n64][k40] f16
// ---------------------------------------------------------------------------
__global__ __launch_bounds__(256) void pack_gemmw(
    const float* __restrict__ W, _Float16* __restrict__ Wp,
    int K, int N, int nch, int mode, float scale,
    int perLayer, int nlayers, int sstride)
{
  int idx = blockIdx.x * 256 + threadIdx.x;
  if (idx >= perLayer * nlayers) return;
  int layer = idx / perLayer;
  int rem = idx - layer*perLayer;
  int unit = rem / PKG;             // cb*nch + ch
  int r2 = rem - unit*PKG;
  int n64 = r2 / 40, kk = r2 - n64*40;
  int cb = unit / nch, ch = unit - cb*nch;
  int gk = ch*32 + kk;
  int np = cb*64 + n64;
  float v = 0.f;
  if (kk < 32 && gk < K) {
    int sc = col_remap(np, mode);
    if (sc >= 0 && sc < N)
      v = W[(size_t)layer*sstride + (size_t)gk*N + sc] * scale;
  }
  Wp[idx] = (_Float16)v;
}

__global__ __launch_bounds__(256) void pack_bias(
    const float* __restrict__ b, float* __restrict__ bp,
    int N, int Np, int mode, float scale, int nlayers)
{
  int idx = blockIdx.x * 256 + threadIdx.x;
  if (idx >= Np * nlayers) return;
  int layer = idx / Np, np = idx - layer*Np;
  int sc = col_remap(np, mode);
  bp[idx] = (sc >= 0 && sc < N) ? b[layer*N + sc] * scale : 0.f;
}

// ---------------------------------------------------------------------------
// Conv weight pack: Wc (OC,IC,3,3) fp32 -> [layer][cb][ch][tap][oc64][k40] f16
// ---------------------------------------------------------------------------
__global__ __launch_bounds__(256) void pack_convw(
    const float* __restrict__ Wc, _Float16* __restrict__ Wp,
    int IC, int OC, int nch, int perLayer, int nlayers, int sstride)
{
  int idx = blockIdx.x * 256 + threadIdx.x;
  if (idx >= perLayer * nlayers) return;
  int layer = idx / perLayer;
  int rem = idx - layer*perLayer;
  int kk = rem % 40;
  int r  = rem / 40;
  int oc = r & 63; r >>= 6;
  int tap = r % 9; r /= 9;
  int ch = r % nch; int cb = r / nch;
  float v = 0.f;
  int goc = cb*64 + oc, gk = ch*32 + kk;
  if (kk < 32 && goc < OC && gk < IC)
    v = Wc[(size_t)layer*sstride + ((size_t)goc * IC + gk) * 9 + tap];
  Wp[idx] = (_Float16)v;
}

// ---------------------------------------------------------------------------
// LayerNorm: 4 rows/block (1/wave), f16 out stride 192 with zero pad.
// ---------------------------------------------------------------------------
__global__ __launch_bounds__(256) void ln2_kernel(
    const float* __restrict__ X, const float* __restrict__ gw,
    const float* __restrict__ gb, _Float16* __restrict__ OUT,
    int mode, int shift)
{
  int wave = threadIdx.x >> 6, lane = threadIdx.x & 63;
  int r = blockIdx.x * 4 + wave;
  int s = (mode == 1) ? win_to_nat(r, shift) : r;
  const float* xr = X + (size_t)s * C;
  float v0 = xr[lane];
  float v1 = xr[lane + 64];
  float v2 = (lane < C - 128) ? xr[lane + 128] : 0.f;
  float sum = v0 + v1 + v2;
  float sq  = v0*v0 + v1*v1 + v2*v2;
  #pragma unroll
  for (int off = 32; off > 0; off >>= 1) {
    sum += __shfl_down(sum, off);
    sq  += __shfl_down(sq,  off);
  }
  sum = __shfl(sum, 0);
  sq  = __shfl(sq,  0);
  float mu  = sum * (1.f / C);
  float var = sq * (1.f / C) - mu * mu;
  float inv = rsqrtf(var + 1e-5f);
  _Float16* orow = OUT + (size_t)r * 192;
  orow[lane]      = (_Float16)((v0 - mu) * inv * gw[lane]      + gb[lane]);
  orow[lane + 64] = (_Float16)((v1 - mu) * inv * gw[lane + 64] + gb[lane + 64]);
  if (lane < C - 128)
    orow[lane + 128] = (_Float16)((v2 - mu) * inv * gw[lane + 128] + gb[lane + 128]);
  if (lane < 12) orow[180 + lane] = (_Float16)0.f;
}

// ---------------------------------------------------------------------------
// MFMA f16 GEMM v2: 128x64 tile, packed weights, f16 A.
// epi: 0 f16 store, 1 f16 gelu store, 2 fp32 residual-add (stride 180).
// grid = (Np/64, M/128), 256 threads.
// ---------------------------------------------------------------------------
__global__ __launch_bounds__(256) void gemm2(
    const _Float16* __restrict__ A, int lda,
    const _Float16* __restrict__ Wp, const float* __restrict__ bias,
    _Float16* __restrict__ O16, int ldo, int nstore,
    float* __restrict__ O32, const float* __restrict__ RES,
    int K, int nch, int amap, int emap, int epi, int shift)
{
  __shared__ _Float16 As[128][40];
  __shared__ _Float16 Bs[64][40];
  int tid  = threadIdx.x;
  int lane = tid & 63, wave = tid >> 6;
  int quad = lane >> 4, ln16 = lane & 15;
  int row0 = blockIdx.y * 128;
  int col0 = blockIdx.x * 64;

  f32x4 acc[2][4];
  #pragma unroll
  for (int mt = 0; mt < 2; ++mt)
    #pragma unroll
    for (int nb = 0; nb < 4; ++nb)
      #pragma unroll
      for (int r = 0; r < 4; ++r) acc[mt][nb][r] = 0.f;

  // precompute A source rows for the 2 staging tasks
  int ar0 = tid >> 1;                  // not used; tasks below
  (void)ar0;

  for (int c = 0; c < nch; ++c) {
    int k0 = c * 32;
    // stage A: 128 rows x 4 segs = 512 tasks
    #pragma unroll
    for (int i = 0; i < 2; ++i) {
      int task = i*256 + tid;
      int ar = task >> 2, ak = (task & 3) * 8;
      int gr = row0 + ar;
      int sr = amap ? ocab_src_row(gr) : gr;
      h8 av;
      #pragma unroll
      for (int j = 0; j < 8; ++j) av[j] = (_Float16)0.f;
      if (sr >= 0) {
        const _Float16* ap = A + (size_t)sr*lda + k0 + ak;
        if (k0 + ak + 8 <= K) av = *(const h8*)ap;
        else {
          #pragma unroll
          for (int j = 0; j < 8; ++j)
            if (k0 + ak + j < K) av[j] = ap[j];
        }
      }
      *(h8*)&As[ar][ak] = av;
    }
    // stage B: contiguous copy of packed 64x40 image (320 h8)
    {
      const h8* src = (const h8*)(Wp + (size_t)(blockIdx.x*nch + c) * PKG);
      h8* dst = (h8*)&Bs[0][0];
      dst[tid] = src[tid];
      if (tid < 64) dst[256 + tid] = src[256 + tid];
    }
    __syncthreads();
    h8 af0 = *(const h8*)&As[wave*32 + ln16][quad*8];
    h8 af1 = *(const h8*)&As[wave*32 + 16 + ln16][quad*8];
    #pragma unroll
    for (int nb = 0; nb < 4; ++nb) {
      h8 bf = *(const h8*)&Bs[nb*16 + ln16][quad*8];
      acc[0][nb] = __builtin_amdgcn_mfma_f32_16x16x32_f16(af0, bf, acc[0][nb], 0, 0, 0);
      acc[1][nb] = __builtin_amdgcn_mfma_f32_16x16x32_f16(af1, bf, acc[1][nb], 0, 0, 0);
    }
    __syncthreads();
  }

  #pragma unroll
  for (int mt = 0; mt < 2; ++mt)
    #pragma unroll
    for (int r = 0; r < 4; ++r) {
      int m = row0 + wave*32 + mt*16 + quad*4 + r;
      int dst = emap ? win_to_nat(m, shift) : m;
      #pragma unroll
      for (int nb = 0; nb < 4; ++nb) {
        int n = col0 + nb*16 + ln16;
        if (n < nstore) {
          float v = acc[mt][nb][r] + bias[n];
          if (epi == 2) {
            v += RES[(size_t)dst*180 + n];
            O32[(size_t)dst*180 + n] = v;
          } else {
            if (epi == 1) v = gelu_exact(v);
            O16[(size_t)dst*ldo + n] = (_Float16)v;
          }
        }
      }
    }
}

// ---------------------------------------------------------------------------
// MFMA f16 3x3 conv. Input fp32 (Xf) or f16 (Xh, stride ldah). Output
// f16 (O16, stride 64, zero-padded cols>=OC) or fp32 residual (O32+RES).
// grid = (ceil(OC/64), NT/64), 256 threads.
// ---------------------------------------------------------------------------
__global__ __launch_bounds__(256) void conv9_mfma(
    const float* __restrict__ Xf, const _Float16* __restrict__ Xh, int ldah,
    const _Float16* __restrict__ Wp, const float* __restrict__ bias,
    const float* __restrict__ scale, const float* __restrict__ RES,
    float* __restrict__ O32, _Float16* __restrict__ O16,
    int IC, int OC, int nch)
{
  __shared__ _Float16 hs[3][66][40];
  __shared__ _Float16 wsm[PKCHUNK];
  int tid  = threadIdx.x;
  int lane = tid & 63, wave = tid >> 6;
  int quad = lane >> 4, ln16 = lane & 15;
  int p0 = blockIdx.y * 64;
  int h  = p0 / WW;
  int w0 = p0 - h * WW;
  int col0 = blockIdx.x * 64;

  f32x4 acc[4];
  #pragma unroll
  for (int nb = 0; nb < 4; ++nb)
    #pragma unroll
    for (int r = 0; r < 4; ++r) acc[nb][r] = 0.f;

  for (int c = 0; c < nch; ++c) {
    int k0 = c * 32;
    {
      const h8* src = (const h8*)(Wp + (size_t)(blockIdx.x * nch + c) * PKCHUNK);
      h8* dst = (h8*)wsm;
      #pragma unroll 3
      for (int idx = tid; idx < PKCHUNK/8; idx += 256) dst[idx] = src[idx];
    }
    for (int idx = tid; idx < 3*66*4; idx += 256) {
      int r    = idx / (66*4);
      int rem  = idx - r*(66*4);
      int px   = rem >> 2;
      int ks   = (rem & 3) * 8;
      int gh = h - 1 + r, gw = w0 - 1 + px;
      h8 hv;
      #pragma unroll
      for (int j = 0; j < 8; ++j) hv[j] = (_Float16)0.f;
      if ((unsigned)gh < (unsigned)HH && (unsigned)gw < (unsigned)WW) {
        if (Xh) {
          const _Float16* sp = Xh + (size_t)(gh*WW + gw) * ldah + k0 + ks;
          h8 t = *(const h8*)sp;
          if (scale) {
            #pragma unroll
            for (int j = 0; j < 8; ++j)
              hv[j] = (_Float16)((float)t[j] * scale[k0 + ks + j]);
          } else hv = t;
        } else {
          const float* sp = Xf + (size_t)(gh*WW + gw) * IC + k0 + ks;
          if (k0 + ks + 8 <= IC) {
            float4 q0 = *(const float4*)sp;
            float4 q1 = *(const float4*)(sp + 4);
            hv[0]=(_Float16)q0.x; hv[1]=(_Float16)q0.y; hv[2]=(_Float16)q0.z; hv[3]=(_Float16)q0.w;
            hv[4]=(_Float16)q1.x; hv[5]=(_Float16)q1.y; hv[6]=(_Float16)q1.z; hv[7]=(_Float16)q1.w;
          } else {
            #pragma unroll
            for (int j = 0; j < 8; ++j)
              if (k0 + ks + j < IC) hv[j] = (_Float16)sp[j];
          }
        }
      }
      *(h8*)&hs[r][px][ks] = hv;
    }
    __syncthreads();
    #pragma unroll
    for (int tap = 0; tap < 9; ++tap) {
      int dyy = tap / 3, dxt = tap % 3;
      h8 af = *(const h8*)&hs[dyy][wave*16 + ln16 + dxt][quad*8];
      #pragma unroll
      for (int nb = 0; nb < 4; ++nb) {
        h8 bf = *(const h8*)&wsm[(tap*64 + nb*16 + ln16)*40 + quad*8];
        acc[nb] = __builtin_amdgcn_mfma_f32_16x16x32_f16(af, bf, acc[nb], 0, 0, 0);
      }
    }
    __syncthreads();
  }

  #pragma unroll
  for (int r = 0; r < 4; ++r) {
    int p = p0 + wave*16 + quad*4 + r;
    #pragma unroll
    for (int nb = 0; nb < 4; ++nb) {
      int oc = col0 + nb*16 + ln16;
      if (O16) {
        float v = (oc < OC) ? acc[nb][r] + bias[oc] : 0.f;
        O16[(size_t)p*64 + oc] = (_Float16)v;
      } else if (oc < OC) {
        float v = acc[nb][r] + bias[oc] + RES[(size_t)p * OC + oc];
        O32[(size_t)p * OC + oc] = v;
      }
    }
  }
}

// ---------------------------------------------------------------------------
// MFMA window attention, f16 QKV (stride 576, heads padded to 32).
// ---------------------------------------------------------------------------
__global__ __launch_bounds__(256) void win_attn_mfma(
    const _Float16* __restrict__ QKV, const float* __restrict__ relb,
    _Float16* __restrict__ OUT, int shift)
{
  __shared__ _Float16 Kf[256][40];
  __shared__ _Float16 Vt[32][264];
  __shared__ _Float16 rbs[962];
  __shared__ unsigned char rg[256];
  int b = blockIdx.x;
  int w = b / HEADS, hd = b - (b / HEADS)*HEADS;
  int tid = threadIdx.x, lane = tid & 63, wave = tid >> 6;
  int quad = lane >> 4, ln16 = lane & 15;
  const _Float16* base = QKV + (size_t)(w*NTW)*576;

  // stage K rows + V transposed
  #pragma unroll
  for (int i = 0; i < 4; ++i) {
    int task = i*256 + tid;
    int row = task >> 2, seg = (task & 3) * 8;
    *(h8*)&Kf[row][seg] = *(const h8*)(base + (size_t)row*576 + 192 + hd*32 + seg);
    h8 hv = *(const h8*)(base + (size_t)row*576 + 384 + hd*32 + seg);
    #pragma unroll
    for (int j = 0; j < 8; ++j) Vt[seg + j][row] = hv[j];
  }
  for (int i = tid; i < 961; i += 256) rbs[i] = (_Float16)relb[i*HEADS + hd];
  if (shift > 0) {
    int wh = w / NWW, ww = w - wh*NWW;
    int rh = wh*WS + (tid >> 4), rw = ww*WS + (tid & 15);
    int regh = (rh < HH - WS) ? 0 : (rh < HH - 8 ? 1 : 2);
    int regw = (rw < WW - WS) ? 0 : (rw < WW - 8 ? 1 : 2);
    rg[tid] = (unsigned char)(regh*3 + regw);
  }

  // Q B-frags direct (pre-scaled at pack time)
  h8 bq[4];
  #pragma unroll
  for (int qi = 0; qi < 4; ++qi) {
    int q = wave*64 + qi*16 + ln16;
    bq[qi] = *(const h8*)(base + (size_t)q*576 + hd*32 + quad*8);
  }
  __syncthreads();

  float mrun[4], lrun[4];
  f32x4 accO[4][2];
  #pragma unroll
  for (int qi = 0; qi < 4; ++qi) {
    mrun[qi] = -1e30f; lrun[qi] = 0.f;
    #pragma unroll
    for (int r = 0; r < 4; ++r) { accO[qi][0][r] = 0.f; accO[qi][1][r] = 0.f; }
  }
  int rgq[4] = {0,0,0,0};
  if (shift > 0) {
    #pragma unroll
    for (int qi = 0; qi < 4; ++qi) rgq[qi] = rg[wave*64 + qi*16 + ln16];
  }
  const f32x4 zero4 = {0.f,0.f,0.f,0.f};

  for (int kb = 0; kb < 4; ++kb) {
    f32x4 st[4][4];
    #pragma unroll
    for (int kt = 0; kt < 4; ++kt) {
      h8 ak = *(const h8*)&Kf[kb*64 + kt*16 + ln16][quad*8];
      #pragma unroll
      for (int qi = 0; qi < 4; ++qi)
        st[kt][qi] = __builtin_amdgcn_mfma_f32_16x16x32_f16(ak, bq[qi], zero4, 0, 0, 0);
    }
    #pragma unroll
    for (int qi = 0; qi < 4; ++qi) {
      int q = wave*64 + qi*16 + ln16;
      int qrr = q >> 4, qcc = q & 15;
      float bmax = -1e30f;
      #pragma unroll
      for (int kt = 0; kt < 4; ++kt) {
        int bidx0 = (qrr - (kb*4 + kt) + 15)*31 + qcc + 15 - quad*4;
        #pragma unroll
        for (int r = 0; r < 4; ++r) {
          float s = st[kt][qi][r] + (float)rbs[bidx0 - r];
          if (shift > 0) {
            int key = kb*64 + kt*16 + quad*4 + r;
            if (rg[key] != rgq[qi]) s -= 100.f;
          }
          st[kt][qi][r] = s;
          bmax = fmaxf(bmax, s);
        }
      }
      bmax = fmaxf(bmax, __shfl_xor(bmax, 16));
      bmax = fmaxf(bmax, __shfl_xor(bmax, 32));
      float mnew  = fmaxf(mrun[qi], bmax);
      float alpha = __expf(mrun[qi] - mnew);
      mrun[qi] = mnew;
      float ps = 0.f;
      #pragma unroll
      for (int kt = 0; kt < 4; ++kt)
        #pragma unroll
        for (int r = 0; r < 4; ++r) {
          float p = __expf(st[kt][qi][r] - mnew);
          st[kt][qi][r] = p; ps += p;
        }
      ps += __shfl_xor(ps, 16);
      ps += __shfl_xor(ps, 32);
      lrun[qi] = lrun[qi]*alpha + ps;
      #pragma unroll
      for (int r = 0; r < 4; ++r) {
        float fr = __shfl(alpha, quad*4 + r);
        accO[qi][0][r] *= fr;
        accO[qi][1][r] *= fr;
      }
    }
    #pragma unroll
    for (int kt = 0; kt < 4; ++kt) {
      int kbase = kb*64 + kt*16 + quad*4;
      h4 bv0 = *(const h4*)&Vt[ln16][kbase];
      h4 bv1 = *(const h4*)&Vt[16 + ln16][kbase];
      #pragma unroll
      for (int qi = 0; qi < 4; ++qi) {
        h4 ap;
        #pragma unroll
        for (int j = 0; j < 4; ++j) ap[j] = (_Float16)st[kt][qi][j];
        accO[qi][0] = __builtin_amdgcn_mfma_f32_16x16x16f16(ap, bv0, accO[qi][0], 0, 0, 0);
        accO[qi][1] = __builtin_amdgcn_mfma_f32_16x16x16f16(ap, bv1, accO[qi][1], 0, 0, 0);
      }
    }
  }

  #pragma unroll
  for (int qi = 0; qi < 4; ++qi) {
    float linv = 1.f / lrun[qi];
    #pragma unroll
    for (int r = 0; r < 4; ++r) {
      float fr = __shfl(linv, quad*4 + r);
      int q = wave*64 + qi*16 + quad*4 + r;
      _Float16* o = OUT + (size_t)(w*NTW + q)*192 + hd*HD;
      o[ln16] = (_Float16)(accO[qi][0][r] * fr);
      if (ln16 < HD - 16) o[16 + ln16] = (_Float16)(accO[qi][1][r] * fr);
    }
  }
}

// ---------------------------------------------------------------------------
// MFMA OCAB attention, f16 Q (stride 192, pre-scaled) + f16 KV (stride 384).
// ---------------------------------------------------------------------------
__global__ __launch_bounds__(256) void ocab_attn_mfma(
    const _Float16* __restrict__ Q, const _Float16* __restrict__ KV,
    _Float16* __restrict__ OUT)
{
  constexpr int CH = 192;
  __shared__ _Float16 Kf[CH][40];
  __shared__ _Float16 Vt[32][200];
  int b = blockIdx.x;
  int w = b / HEADS, hd = b - (b / HEADS)*HEADS;
  int tid = threadIdx.x, lane = tid & 63, wave = tid >> 6;
  int quad = lane >> 4, ln16 = lane & 15;

  h8 bq[4];
  #pragma unroll
  for (int qi = 0; qi < 4; ++qi) {
    int q = wave*64 + qi*16 + ln16;
    bq[qi] = *(const h8*)(Q + (size_t)(w*NTW + q)*192 + hd*32 + quad*8);
  }

  float mrun[4], lrun[4];
  f32x4 accO[4][2];
  #pragma unroll
  for (int qi = 0; qi < 4; ++qi) {
    mrun[qi] = -1e30f; lrun[qi] = 0.f;
    #pragma unroll
    for (int r = 0; r < 4; ++r) { accO[qi][0][r] = 0.f; accO[qi][1][r] = 0.f; }
  }
  const f32x4 zero4 = {0.f,0.f,0.f,0.f};

  for (int ch = 0; ch < 3; ++ch) {
    __syncthreads();
    #pragma unroll
    for (int i = 0; i < 3; ++i) {
      int task = i*256 + tid;
      int row = task >> 2, seg = (task & 3) * 8;
      const _Float16* kvr = KV + (size_t)(w*NKV + ch*CH + row)*384;
      *(h8*)&Kf[row][seg] = *(const h8*)(kvr + hd*32 + seg);
      h8 hv = *(const h8*)(kvr + 192 + hd*32 + seg);
      #pragma unroll
      for (int j = 0; j < 8; ++j) Vt[seg + j][row] = hv[j];
    }
    __syncthreads();

    for (int kb = 0; kb < 3; ++kb) {
      f32x4 st[4][4];
      #pragma unroll
      for (int kt = 0; kt < 4; ++kt) {
        h8 ak = *(const h8*)&Kf[kb*64 + kt*16 + ln16][quad*8];
        #pragma unroll
        for (int qi = 0; qi < 4; ++qi)
          st[kt][qi] = __builtin_amdgcn_mfma_f32_16x16x32_f16(ak, bq[qi], zero4, 0, 0, 0);
      }
      #pragma unroll
      for (int qi = 0; qi < 4; ++qi) {
        float bmax = -1e30f;
        #pragma unroll
        for (int kt = 0; kt < 4; ++kt)
          #pragma unroll
          for (int r = 0; r < 4; ++r) bmax = fmaxf(bmax, st[kt][qi][r]);
        bmax = fmaxf(bmax, __shfl_xor(bmax, 16));
        bmax = fmaxf(bmax, __shfl_xor(bmax, 32));
        float mnew  = fmaxf(mrun[qi], bmax);
        float alpha = __expf(mrun[qi] - mnew);
        mrun[qi] = mnew;
        float ps = 0.f;
        #pragma unroll
        for (int kt = 0; kt < 4; ++kt)
          #pragma unroll
          for (int r = 0; r < 4; ++r) {
            float p = __expf(st[kt][qi][r] - mnew);
            st[kt][qi][r] = p; ps += p;
          }
        ps += __shfl_xor(ps, 16);
        ps += __shfl_xor(ps, 32);
        lrun[qi] = lrun[qi]*alpha + ps;
        #pragma unroll
        for (int r = 0; r < 4; ++r) {
          float fr = __shfl(alpha, quad*4 + r);
          accO[qi][0][r] *= fr;
          accO[qi][1][r] *= fr;
        }
      }
      #pragma unroll
      for (int kt = 0; kt < 4; ++kt) {
        int kbase = kb*64 + kt*16 + quad*4;
        h4 bv0 = *(const h4*)&Vt[ln16][kbase];
        h4 bv1 = *(const h4*)&Vt[16 + ln16][kbase];
        #pragma unroll
        for (int qi = 0; qi < 4; ++qi) {
          h4 ap;
          #pragma unroll
          for (int j = 0; j < 4; ++j) ap[j] = (_Float16)st[kt][qi][j];
          accO[qi][0] = __builtin_amdgcn_mfma_f32_16x16x16f16(ap, bv0, accO[qi][0], 0, 0, 0);
          accO[qi][1] = __builtin_amdgcn_mfma_f32_16x16x16f16(ap, bv1, accO[qi][1], 0, 0, 0);
        }
      }
    }
  }

  #pragma unroll
  for (int qi = 0; qi < 4; ++qi) {
    float linv = 1.f / lrun[qi];
    #pragma unroll
    for (int r = 0; r < 4; ++r) {
      float fr = __shfl(linv, quad*4 + r);
      int q = wave*64 + qi*16 + quad*4 + r;
      _Float16* o = OUT + (size_t)(w*NTW + q)*192 + hd*HD;
      o[ln16] = (_Float16)(accO[qi][0][r] * fr);
      if (ln16 < HD - 16) o[16 + ln16] = (_Float16)(accO[qi][1][r] * fr);
    }
  }
}

// ---------------------------------------------------------------------------
// Column sums of COMP f16 (stride 64) -> S[60] via atomics. grid 288 x 256.
// ---------------------------------------------------------------------------
__global__ __launch_bounds__(256) void colsum_kernel(
    const _Float16* __restrict__ COMP, float* __restrict__ S)
{
  int tid = threadIdx.x;
  int seg = tid & 7, rb = tid >> 3;
  int row0 = blockIdx.x * 128;
  float a[8] = {};
  #pragma unroll
  for (int i = 0; i < 4; ++i) {
    int row = row0 + i*32 + rb;
    h8 v = *(const h8*)(COMP + (size_t)row*64 + seg*8);
    #pragma unroll
    for (int j = 0; j < 8; ++j) a[j] += (float)v[j];
  }
  __shared__ float sA[64];
  if (tid < 64) sA[tid] = 0.f;
  __syncthreads();
  #pragma unroll
  for (int j = 0; j < 8; ++j) atomicAdd(&sA[seg*8 + j], a[j]);
  __syncthreads();
  if (tid < 60) atomicAdd(&S[tid], sA[tid]);
}

__global__ __launch_bounds__(64) void se_kernel(
    const float* __restrict__ S, const float* __restrict__ w1,
    const float* __restrict__ b1, const float* __restrict__ w2,
    const float* __restrict__ b2, float* __restrict__ G)
{
  __shared__ float hid[CSE];
  int t = threadIdx.x;
  if (t < CSE) {
    float a = b1[t];
    for (int c = 0; c < CCH; ++c) a += (S[c] * (1.f/NT)) * w1[c * CSE + t];
    hid[t] = fmaxf(a, 0.f);
  }
  __syncthreads();
  if (t < CCH) {
    float a = b2[t];
    #pragma unroll
    for (int j = 0; j < CSE; ++j) a += hid[j] * w2[j * CCH + t];
    G[t] = 1.f / (1.f + __expf(-a));
  }
}

// ---------------------------------------------------------------------------

extern "C" void kernel_launch(void* const* d_in, const int* in_sizes, int n_in,
                              void* d_out, int out_size, void* d_ws, size_t ws_size,
                              hipStream_t stream) {
  const float* x_in   = (const float*)d_in[0];
  const float* n1w    = (const float*)d_in[1];
  const float* n1b    = (const float*)d_in[2];
  const float* qkvw   = (const float*)d_in[3];
  const float* qkvb   = (const float*)d_in[4];
  const float* relb   = (const float*)d_in[5];
  const float* projw  = (const float*)d_in[6];
  const float* projb  = (const float*)d_in[7];
  const float* ccw    = (const float*)d_in[8];
  const float* ccb    = (const float*)d_in[9];
  const float* ca1w   = (const float*)d_in[10];
  const float* ca1b   = (const float*)d_in[11];
  const float* ca2w   = (const float*)d_in[12];
  const float* ca2b   = (const float*)d_in[13];
  const float* cew    = (const float*)d_in[14];
  const float* ceb    = (const float*)d_in[15];
  const float* n2w    = (const float*)d_in[16];
  const float* n2b    = (const float*)d_in[17];
  const float* m1w    = (const float*)d_in[18];
  const float* m1b    = (const float*)d_in[19];
  const float* m2w    = (const float*)d_in[20];
  const float* m2b    = (const float*)d_in[21];
  const float* onw    = (const float*)d_in[22];
  const float* onb    = (const float*)d_in[23];
  const float* oqw    = (const float*)d_in[24];
  const float* oqb    = (const float*)d_in[25];
  const float* okvw   = (const float*)d_in[26];
  const float* okvb   = (const float*)d_in[27];
  const float* opw    = (const float*)d_in[28];
  const float* opb    = (const float*)d_in[29];
  const float* convw  = (const float*)d_in[30];
  const float* convb  = (const float*)d_in[31];

  float* ws   = (float*)d_ws;
  float*     X    = ws + OFF_X;
  _Float16*  A    = (_Float16*)(ws + OFF_A);
  _Float16*  Bq   = (_Float16*)(ws + OFF_B);
  _Float16*  COMP = (_Float16*)(ws + OFF_COMP);
  float*     S    = ws + OFF_S;
  float*     G    = ws + OFF_G;
  _Float16*  QKV  = (_Float16*)(ws + OFF_QKV);   // also KV / GELU buffer
  _Float16*  PK   = (_Float16*)(ws + OFF_PK);
  float*     PB   = ws + OFF_PB;

  float* qkvB = PB;            // 6*576
  float* oqB  = PB + 6*576;    // 192
  float* okvB = oqB + 192;     // 384

  const float scl = 0.18257418583505536f;  // 1/sqrt(30)

  (void)hipMemcpyAsync(X, x_in, (size_t)NT * C * sizeof(float),
                       hipMemcpyDeviceToDevice, stream);

  // ---- pack all weights/biases (once per launch) ----
  #define GRID(n) dim3(((n)+255)/256)
  pack_gemmw<<<GRID(6*QKV_PL), 256, 0, stream>>>(qkvw, PK+PO_QKV, 180, 540, 6, 1, 1.f, QKV_PL, 6, 180*540);
  pack_gemmw<<<GRID(6*PROJ_PL),256, 0, stream>>>(projw, PK+PO_PROJ,180, 180, 6, 0, 1.f, PROJ_PL,6, 180*180);
  pack_gemmw<<<GRID(6*M1_PL), 256, 0, stream>>>(m1w,  PK+PO_M1,  180, 360, 6, 0, 1.f, M1_PL,  6, 180*360);
  pack_gemmw<<<GRID(6*M2_PL), 256, 0, stream>>>(m2w,  PK+PO_M2,  360, 180,12, 0, 1.f, M2_PL,  6, 360*180);
  pack_gemmw<<<GRID(OQ_PL),   256, 0, stream>>>(oqw,  PK+PO_OQ,  180, 180, 6, 3, scl, OQ_PL,  1, 0);
  pack_gemmw<<<GRID(OKV_PL),  256, 0, stream>>>(okvw, PK+PO_OKV, 180, 360, 6, 2, 1.f, OKV_PL, 1, 0);
  pack_gemmw<<<GRID(OP_PL),   256, 0, stream>>>(opw,  PK+PO_OP,  180, 180, 6, 0, 1.f, OP_PL,  1, 0);
  pack_convw<<<GRID(6*CC_PL), 256, 0, stream>>>(ccw,  PK+PO_CC,  180,  60, 6, CC_PL, 6, 60*180*9);
  pack_convw<<<GRID(6*CE_PL), 256, 0, stream>>>(cew,  PK+PO_CE,   60, 180, 2, CE_PL, 6, 180*60*9);
  pack_convw<<<GRID(FIN_PL),  256, 0, stream>>>(convw,PK+PO_FIN, 180, 180, 6, FIN_PL,1, 0);
  pack_bias<<<GRID(6*576), 256, 0, stream>>>(qkvb, qkvB, 540, 576, 1, 1.f, 6);
  pack_bias<<<GRID(192),   256, 0, stream>>>(oqb,  oqB,  180, 192, 3, scl, 1);
  pack_bias<<<GRID(384),   256, 0, stream>>>(okvb, okvB, 360, 384, 2, 1.f, 1);

  const int MB128 = NT / 128;   // 288
  const int MB64  = NT / 64;    // 576

  for (int i = 0; i < DEPTH; ++i) {
    int shift = (i % 2 == 0) ? 0 : WS / 2;
    // LN1 + roll + window partition -> A f16
    ln2_kernel<<<NT/4, 256, 0, stream>>>(X, n1w + i*C, n1b + i*C, A, 1, shift);
    // QKV (padded 576) f16
    gemm2<<<dim3(9, MB128), 256, 0, stream>>>(
        A, 192, PK+PO_QKV + (size_t)i*QKV_PL, qkvB + i*576,
        QKV, 576, 576, nullptr, nullptr, 180, 6, 0, 0, 0, 0);
    // window MSA -> A f16
    win_attn_mfma<<<NWIN*HEADS, 256, 0, stream>>>(
        QKV, relb + (size_t)i*961*HEADS, A, shift);
    // X += reverse(A @ proj)
    gemm2<<<dim3(3, MB128), 256, 0, stream>>>(
        A, 192, PK+PO_PROJ + (size_t)i*PROJ_PL, projb + i*C,
        nullptr, 0, 180, X, X, 180, 6, 0, 1, 2, shift);
    // COMP = conv cc (fp32 in, f16 out)
    conv9_mfma<<<dim3(1, MB64), 256, 0, stream>>>(
        X, nullptr, 0, PK+PO_CC + (size_t)i*CC_PL, ccb + i*CCH,
        nullptr, nullptr, nullptr, COMP, 180, 60, 6);
    // SE gate
    (void)hipMemsetAsync(S, 0, 64*sizeof(float), stream);
    colsum_kernel<<<288, 256, 0, stream>>>(COMP, S);
    se_kernel<<<1, 64, 0, stream>>>(
        S, ca1w + (size_t)i*CCH*CSE, ca1b + (size_t)i*CSE,
        ca2w + (size_t)i*CSE*CCH, ca2b + (size_t)i*CCH, G);
    // X += conv ce (f16 in w/ gate, fp32 residual out)
    conv9_mfma<<<dim3(3, MB64), 256, 0, stream>>>(
        nullptr, COMP, 64, PK+PO_CE + (size_t)i*CE_PL, ceb + i*C,
        G, X, X, nullptr, 60, 180, 2);
    // MLP
    ln2_kernel<<<NT/4, 256, 0, stream>>>(X, n2w + i*C, n2b + i*C, A, 0, 0);
    gemm2<<<dim3(6, MB128), 256, 0, stream>>>(
        A, 192, PK+PO_M1 + (size_t)i*M1_PL, m1b + i*HID,
        QKV, 384, 360, nullptr, nullptr, 180, 6, 0, 0, 1, 0);
    gemm2<<<dim3(3, MB128), 256, 0, stream>>>(
        QKV, 384, PK+PO_M2 + (size_t)i*M2_PL, m2b + i*C,
        nullptr, 0, 180, X, X, 360, 12, 0, 0, 2, 0);
  }

  // ---- OCAB ----
  ln2_kernel<<<NT/4, 256, 0, stream>>>(X, onw, onb, A, 1, 0);
  gemm2<<<dim3(3, MB128), 256, 0, stream>>>(
      A, 192, PK+PO_OQ, oqB, Bq, 192, 192, nullptr, nullptr, 180, 6, 0, 0, 0, 0);
  gemm2<<<dim3(6, NWIN*NKV/128), 256, 0, stream>>>(
      A, 192, PK+PO_OKV, okvB, QKV, 384, 384, nullptr, nullptr, 180, 6, 1, 0, 0, 0);
  ocab_attn_mfma<<<NWIN*HEADS, 256, 0, stream>>>(Bq, QKV, A);
  gemm2<<<dim3(3, MB128), 256, 0, stream>>>(
      A, 192, PK+PO_OP, opb, nullptr, 0, 180, X, X, 180, 6, 0, 1, 2, 0);

  // ---- final conv + global shortcut -> d_out ----
  conv9_mfma<<<dim3(3, MB64), 256, 0, stream>>>(
      X, nullptr, 0, PK+PO_FIN, convb, nullptr, x_in,
      (float*)d_out, nullptr, 180, 180, 6);
}

// Round 7
// 2483.223 us; speedup vs baseline: 3.7544x; 1.1393x over previous
//
#include <hip/hip_runtime.h>
#include <math.h>

// ---------------------------------------------------------------------------
// HAT block — fp32 residual stream, f16 activations, MFMA everywhere.
// Weights pre-packed per launch in lane-contiguous fragment order so waves
// load B-fragments directly global->VGPR (no LDS round-trip).
// ---------------------------------------------------------------------------

#define DEV __device__ __forceinline__

constexpr int HH   = 192;
constexpr int WW   = 192;
constexpr int NT   = HH * WW;     // 36864
constexpr int C    = 180;
constexpr int HEADS= 6;
constexpr int HD   = 30;
constexpr int WS   = 16;
constexpr int NWW  = WW / WS;     // 12
constexpr int NWIN = 144;
constexpr int NTW  = 256;
constexpr int OWS  = 24;
constexpr int NKV  = OWS*OWS;     // 576
constexpr int CCH  = 60;
constexpr int CSE  = 6;
constexpr int HID  = 360;
constexpr int DEPTH= 6;

typedef _Float16 h8   __attribute__((ext_vector_type(8)));
typedef _Float16 h4   __attribute__((ext_vector_type(4)));
typedef float    f32x4 __attribute__((ext_vector_type(4)));

constexpr int PKG = 2048;            // gemm pack unit: [nb4][lane64][j8]
constexpr int PKC = 18432;           // conv pack unit: [tap9][nb4][lane64][j8]

// per-layer pack sizes (halfs)
constexpr int QKV_PL = 9*6*PKG;
constexpr int PROJ_PL= 3*6*PKG;
constexpr int M1_PL  = 6*6*PKG;
constexpr int M2_PL  = 3*12*PKG;
constexpr int OQ_PL  = 3*6*PKG;
constexpr int OKV_PL = 6*6*PKG;
constexpr int OP_PL  = 3*6*PKG;
constexpr int CC_PL  = 1*6*PKC;
constexpr int CE_PL  = 3*2*PKC;
constexpr int FIN_PL = 3*6*PKC;

constexpr size_t PO_QKV = 0;
constexpr size_t PO_PROJ= PO_QKV + 6ull*QKV_PL;
constexpr size_t PO_M1  = PO_PROJ+ 6ull*PROJ_PL;
constexpr size_t PO_M2  = PO_M1  + 6ull*M1_PL;
constexpr size_t PO_OQ  = PO_M2  + 6ull*M2_PL;
constexpr size_t PO_OKV = PO_OQ  + OQ_PL;
constexpr size_t PO_OP  = PO_OKV + OKV_PL;
constexpr size_t PO_CC  = PO_OP  + OP_PL;
constexpr size_t PO_CE  = PO_CC  + 6ull*CC_PL;
constexpr size_t PO_FIN = PO_CE  + 6ull*CE_PL;
constexpr size_t PK_HALFS = PO_FIN + FIN_PL;

// workspace offsets (floats)
constexpr size_t OFF_X    = 0;
constexpr size_t OFF_A    = OFF_X    + (size_t)NT*C;
constexpr size_t OFF_B    = OFF_A    + (size_t)NT*C;
constexpr size_t OFF_COMP = OFF_B    + (size_t)NT*C;
constexpr size_t OFF_S    = OFF_COMP + (size_t)NT*CCH;
constexpr size_t OFF_G    = OFF_S    + 64;
constexpr size_t OFF_QKV  = OFF_G    + 64;
constexpr size_t OFF_PK   = OFF_QKV  + 16000000;
constexpr size_t OFF_PB   = OFF_PK   + PK_HALFS/2 + 8;

DEV int win_to_nat(int r, int shift) {
  int w   = r >> 8;
  int pos = r & 255;
  int wh = w / NWW, ww = w - wh*NWW;
  int rh = wh*WS + (pos >> 4);
  int rw = ww*WS + (pos & 15);
  int sh = rh + shift; if (sh >= HH) sh -= HH;
  int sw = rw + shift; if (sw >= WW) sw -= WW;
  return sh*WW + sw;
}

DEV int ocab_src_row(int gr) {
  int w = gr / NKV;
  int t = gr - w*NKV;
  int wh = w / NWW, ww = w - wh*NWW;
  int i = t / OWS, j = t - i*OWS;
  int gh = wh*WS - 4 + i;
  int gw = ww*WS - 4 + j;
  if ((unsigned)gh >= (unsigned)HH || (unsigned)gw >= (unsigned)WW) return -1;
  return (((gh >> 4)*NWW + (gw >> 4)) << 8) + ((gh & 15) << 4) + (gw & 15);
}

DEV float gelu_exact(float v) {
  return 0.5f * v * (1.0f + erff(v * 0.70710678118654752f));
}

// col remap for padded layouts. returns src col or -1 (zero pad)
DEV int col_remap(int np, int mode) {
  if (mode == 0) return np;
  int d = np & 31, hh = (np >> 5) % 6;
  if (d >= 30) return -1;
  if (mode == 1) { int third = np / 192; return third*180 + hh*30 + d; }
  if (mode == 2) { int half  = np / 192; return half *180 + hh*30 + d; }
  return hh*30 + d;
}

// ---------------------------------------------------------------------------
// GEMM weight pack: W (K,N) fp32 -> [layer][cb][ch][nb][lane][j] f16
// frag(lane=quad*16+l16, nb) = W[k=ch*32+quad*8+j][n=cb*64+nb*16+l16]
// ---------------------------------------------------------------------------
__global__ __launch_bounds__(256) void pack_gemmw(
    const float* __restrict__ W, _Float16* __restrict__ Wp,
    int K, int N, int nch, int mode, float scale,
    int perLayer, int nlayers, int sstride)
{
  int idx = blockIdx.x * 256 + threadIdx.x;
  if (idx >= perLayer * nlayers) return;
  int layer = idx / perLayer;
  int rem = idx - layer*perLayer;
  int unit = rem >> 11;
  int r2 = rem & 2047;
  int nb = r2 >> 9;
  int lane = (r2 >> 3) & 63;
  int j = r2 & 7;
  int cb = unit / nch, ch = unit - cb*nch;
  int quad = lane >> 4, l16 = lane & 15;
  int np = cb*64 + nb*16 + l16;
  int gk = ch*32 + quad*8 + j;
  float v = 0.f;
  if (gk < K) {
    int sc = col_remap(np, mode);
    if (sc >= 0 && sc < N)
      v = W[(size_t)layer*sstride + (size_t)gk*N + sc] * scale;
  }
  Wp[idx] = (_Float16)v;
}

__global__ __launch_bounds__(256) void pack_bias(
    const float* __restrict__ b, float* __restrict__ bp,
    int N, int Np, int mode, float scale, int nlayers)
{
  int idx = blockIdx.x * 256 + threadIdx.x;
  if (idx >= Np * nlayers) return;
  int layer = idx / Np, np = idx - layer*Np;
  int sc = col_remap(np, mode);
  bp[idx] = (sc >= 0 && sc < N) ? b[layer*N + sc] * scale : 0.f;
}

// ---------------------------------------------------------------------------
// Conv weight pack: Wc (OC,IC,3,3) fp32 -> [layer][cb][ch][tap][nb][lane][j]
// ---------------------------------------------------------------------------
__global__ __launch_bounds__(256) void pack_convw(
    const float* __restrict__ Wc, _Float16* __restrict__ Wp,
    int IC, int OC, int nch, int perLayer, int nlayers, int sstride)
{
  int idx = blockIdx.x * 256 + threadIdx.x;
  if (idx >= perLayer * nlayers) return;
  int layer = idx / perLayer;
  int rem = idx - layer*perLayer;
  int unit = rem / PKC;
  int w2 = rem - unit*PKC;
  int tap = w2 >> 11;
  int r2 = w2 & 2047;
  int nb = r2 >> 9;
  int lane = (r2 >> 3) & 63;
  int j = r2 & 7;
  int cb = unit / nch, ch = unit - cb*nch;
  int quad = lane >> 4, l16 = lane & 15;
  int oc = cb*64 + nb*16 + l16;
  int gk = ch*32 + quad*8 + j;
  float v = 0.f;
  if (oc < OC && gk < IC)
    v = Wc[(size_t)layer*sstride + ((size_t)oc * IC + gk) * 9 + tap];
  Wp[idx] = (_Float16)v;
}

// ---------------------------------------------------------------------------
// LayerNorm: 4 rows/block (1/wave), f16 out stride 192 with zero pad.
// ---------------------------------------------------------------------------
__global__ __launch_bounds__(256) void ln2_kernel(
    const float* __restrict__ X, const float* __restrict__ gw,
    const float* __restrict__ gb, _Float16* __restrict__ OUT,
    int mode, int shift)
{
  int wave = threadIdx.x >> 6, lane = threadIdx.x & 63;
  int r = blockIdx.x * 4 + wave;
  int s = (mode == 1) ? win_to_nat(r, shift) : r;
  const float* xr = X + (size_t)s * C;
  float v0 = xr[lane];
  float v1 = xr[lane + 64];
  float v2 = (lane < C - 128) ? xr[lane + 128] : 0.f;
  float sum = v0 + v1 + v2;
  float sq  = v0*v0 + v1*v1 + v2*v2;
  #pragma unroll
  for (int off = 32; off > 0; off >>= 1) {
    sum += __shfl_down(sum, off);
    sq  += __shfl_down(sq,  off);
  }
  sum = __shfl(sum, 0);
  sq  = __shfl(sq,  0);
  float mu  = sum * (1.f / C);
  float var = sq * (1.f / C) - mu * mu;
  float inv = rsqrtf(var + 1e-5f);
  _Float16* orow = OUT + (size_t)r * 192;
  orow[lane]      = (_Float16)((v0 - mu) * inv * gw[lane]      + gb[lane]);
  orow[lane + 64] = (_Float16)((v1 - mu) * inv * gw[lane + 64] + gb[lane + 64]);
  if (lane < C - 128)
    orow[lane + 128] = (_Float16)((v2 - mu) * inv * gw[lane + 128] + gb[lane + 128]);
  if (lane < 12) orow[180 + lane] = (_Float16)0.f;
}

// ---------------------------------------------------------------------------
// MFMA f16 GEMM: 128x64 tile, packed weights (B frags direct from global).
// epi: 0 f16 store, 1 f16 gelu store, 2 fp32 residual-add (stride 180).
// ---------------------------------------------------------------------------
__global__ __launch_bounds__(256) void gemm2(
    const _Float16* __restrict__ A, int lda,
    const _Float16* __restrict__ Wp, const float* __restrict__ bias,
    _Float16* __restrict__ O16, int ldo, int nstore,
    float* __restrict__ O32, const float* __restrict__ RES,
    int K, int nch, int amap, int emap, int epi, int shift)
{
  __shared__ _Float16 As[128][40];
  int tid  = threadIdx.x;
  int lane = tid & 63, wave = tid >> 6;
  int quad = lane >> 4, ln16 = lane & 15;
  int row0 = blockIdx.y * 128;
  int col0 = blockIdx.x * 64;

  f32x4 acc[2][4];
  #pragma unroll
  for (int mt = 0; mt < 2; ++mt)
    #pragma unroll
    for (int nb = 0; nb < 4; ++nb)
      #pragma unroll
      for (int r = 0; r < 4; ++r) acc[mt][nb][r] = 0.f;

  const _Float16* wlane = Wp + (size_t)lane*8;

  for (int c = 0; c < nch; ++c) {
    int k0 = c * 32;
    if (c) __syncthreads();
    // stage A: 128 rows x 4 segs = 512 tasks
    #pragma unroll
    for (int i = 0; i < 2; ++i) {
      int task = i*256 + tid;
      int ar = task >> 2, ak = (task & 3) * 8;
      int gr = row0 + ar;
      int sr = amap ? ocab_src_row(gr) : gr;
      h8 av;
      #pragma unroll
      for (int j = 0; j < 8; ++j) av[j] = (_Float16)0.f;
      if (sr >= 0) {
        const _Float16* ap = A + (size_t)sr*lda + k0 + ak;
        if (k0 + ak + 8 <= K) av = *(const h8*)ap;
        else {
          #pragma unroll
          for (int j = 0; j < 8; ++j)
            if (k0 + ak + j < K) av[j] = ap[j];
        }
      }
      *(h8*)&As[ar][ak] = av;
    }
    // B frags direct from global (packed, lane-contiguous)
    h8 bf[4];
    #pragma unroll
    for (int nb = 0; nb < 4; ++nb)
      bf[nb] = *(const h8*)(wlane + (size_t)(blockIdx.x*nch + c)*PKG + (size_t)nb*512);
    __syncthreads();
    h8 af0 = *(const h8*)&As[wave*32 + ln16][quad*8];
    h8 af1 = *(const h8*)&As[wave*32 + 16 + ln16][quad*8];
    #pragma unroll
    for (int nb = 0; nb < 4; ++nb) {
      acc[0][nb] = __builtin_amdgcn_mfma_f32_16x16x32_f16(af0, bf[nb], acc[0][nb], 0, 0, 0);
      acc[1][nb] = __builtin_amdgcn_mfma_f32_16x16x32_f16(af1, bf[nb], acc[1][nb], 0, 0, 0);
    }
  }

  #pragma unroll
  for (int mt = 0; mt < 2; ++mt)
    #pragma unroll
    for (int r = 0; r < 4; ++r) {
      int m = row0 + wave*32 + mt*16 + quad*4 + r;
      int dst = emap ? win_to_nat(m, shift) : m;
      #pragma unroll
      for (int nb = 0; nb < 4; ++nb) {
        int n = col0 + nb*16 + ln16;
        if (n < nstore) {
          float v = acc[mt][nb][r] + bias[n];
          if (epi == 2) {
            v += RES[(size_t)dst*180 + n];
            O32[(size_t)dst*180 + n] = v;
          } else {
            if (epi == 1) v = gelu_exact(v);
            O16[(size_t)dst*ldo + n] = (_Float16)v;
          }
        }
      }
    }
}

// ---------------------------------------------------------------------------
// MFMA f16 3x3 conv. Halo in LDS (15.8 KB); weights direct global->VGPR with
// one-tap lookahead. grid = (ceil(OC/64), NT/64), 256 threads.
// ---------------------------------------------------------------------------
__global__ __launch_bounds__(256) void conv9_mfma(
    const float* __restrict__ Xf, const _Float16* __restrict__ Xh, int ldah,
    const _Float16* __restrict__ Wp, const float* __restrict__ bias,
    const float* __restrict__ scale, const float* __restrict__ RES,
    float* __restrict__ O32, _Float16* __restrict__ O16,
    int IC, int OC, int nch)
{
  __shared__ _Float16 hs[3][66][40];
  int tid  = threadIdx.x;
  int lane = tid & 63, wave = tid >> 6;
  int quad = lane >> 4, ln16 = lane & 15;
  int p0 = blockIdx.y * 64;
  int h  = p0 / WW;
  int w0 = p0 - h * WW;
  int col0 = blockIdx.x * 64;

  f32x4 acc[4];
  #pragma unroll
  for (int nb = 0; nb < 4; ++nb)
    #pragma unroll
    for (int r = 0; r < 4; ++r) acc[nb][r] = 0.f;

  for (int c = 0; c < nch; ++c) {
    int k0 = c * 32;
    if (c) __syncthreads();
    for (int idx = tid; idx < 3*66*4; idx += 256) {
      int r    = idx / (66*4);
      int rem  = idx - r*(66*4);
      int px   = rem >> 2;
      int ks   = (rem & 3) * 8;
      int gh = h - 1 + r, gw = w0 - 1 + px;
      h8 hv;
      #pragma unroll
      for (int j = 0; j < 8; ++j) hv[j] = (_Float16)0.f;
      if ((unsigned)gh < (unsigned)HH && (unsigned)gw < (unsigned)WW) {
        if (Xh) {
          const _Float16* sp = Xh + (size_t)(gh*WW + gw) * ldah + k0 + ks;
          h8 t = *(const h8*)sp;
          if (scale) {
            #pragma unroll
            for (int j = 0; j < 8; ++j)
              hv[j] = (_Float16)((float)t[j] * scale[k0 + ks + j]);
          } else hv = t;
        } else {
          const float* sp = Xf + (size_t)(gh*WW + gw) * IC + k0 + ks;
          if (k0 + ks + 8 <= IC) {
            float4 q0 = *(const float4*)sp;
            float4 q1 = *(const float4*)(sp + 4);
            hv[0]=(_Float16)q0.x; hv[1]=(_Float16)q0.y; hv[2]=(_Float16)q0.z; hv[3]=(_Float16)q0.w;
            hv[4]=(_Float16)q1.x; hv[5]=(_Float16)q1.y; hv[6]=(_Float16)q1.z; hv[7]=(_Float16)q1.w;
          } else {
            #pragma unroll
            for (int j = 0; j < 8; ++j)
              if (k0 + ks + j < IC) hv[j] = (_Float16)sp[j];
          }
        }
      }
      *(h8*)&hs[r][px][ks] = hv;
    }
    __syncthreads();

    const _Float16* wpc = Wp + (size_t)(blockIdx.x*nch + c) * PKC + (size_t)lane*8;
    h8 bf[4];
    #pragma unroll
    for (int nb = 0; nb < 4; ++nb)
      bf[nb] = *(const h8*)(wpc + (size_t)nb*512);
    #pragma unroll
    for (int tap = 0; tap < 9; ++tap) {
      h8 bfn[4];
      if (tap < 8) {
        #pragma unroll
        for (int nb = 0; nb < 4; ++nb)
          bfn[nb] = *(const h8*)(wpc + (size_t)(tap+1)*2048 + (size_t)nb*512);
      }
      int dyy = tap / 3, dxt = tap - dyy*3;
      h8 af = *(const h8*)&hs[dyy][wave*16 + ln16 + dxt][quad*8];
      #pragma unroll
      for (int nb = 0; nb < 4; ++nb)
        acc[nb] = __builtin_amdgcn_mfma_f32_16x16x32_f16(af, bf[nb], acc[nb], 0, 0, 0);
      if (tap < 8) {
        #pragma unroll
        for (int nb = 0; nb < 4; ++nb) bf[nb] = bfn[nb];
      }
    }
  }

  #pragma unroll
  for (int r = 0; r < 4; ++r) {
    int p = p0 + wave*16 + quad*4 + r;
    #pragma unroll
    for (int nb = 0; nb < 4; ++nb) {
      int oc = col0 + nb*16 + ln16;
      if (O16) {
        float v = (oc < OC) ? acc[nb][r] + bias[oc] : 0.f;
        O16[(size_t)p*64 + oc] = (_Float16)v;
      } else if (oc < OC) {
        float v = acc[nb][r] + bias[oc] + RES[(size_t)p * OC + oc];
        O32[(size_t)p * OC + oc] = v;
      }
    }
  }
}

// ---------------------------------------------------------------------------
// MFMA window attention, f16 QKV (stride 576, heads padded to 32).
// ---------------------------------------------------------------------------
__global__ __launch_bounds__(256) void win_attn_mfma(
    const _Float16* __restrict__ QKV, const float* __restrict__ relb,
    _Float16* __restrict__ OUT, int shift)
{
  __shared__ _Float16 Kf[256][40];
  __shared__ _Float16 Vt[32][264];
  __shared__ _Float16 rbs[962];
  __shared__ unsigned char rg[256];
  int b = blockIdx.x;
  int w = b / HEADS, hd = b - (b / HEADS)*HEADS;
  int tid = threadIdx.x, lane = tid & 63, wave = tid >> 6;
  int quad = lane >> 4, ln16 = lane & 15;
  const _Float16* base = QKV + (size_t)(w*NTW)*576;

  #pragma unroll
  for (int i = 0; i < 4; ++i) {
    int task = i*256 + tid;
    int row = task >> 2, seg = (task & 3) * 8;
    *(h8*)&Kf[row][seg] = *(const h8*)(base + (size_t)row*576 + 192 + hd*32 + seg);
    h8 hv = *(const h8*)(base + (size_t)row*576 + 384 + hd*32 + seg);
    #pragma unroll
    for (int j = 0; j < 8; ++j) Vt[seg + j][row] = hv[j];
  }
  for (int i = tid; i < 961; i += 256) rbs[i] = (_Float16)relb[i*HEADS + hd];
  if (shift > 0) {
    int wh = w / NWW, ww = w - wh*NWW;
    int rh = wh*WS + (tid >> 4), rw = ww*WS + (tid & 15);
    int regh = (rh < HH - WS) ? 0 : (rh < HH - 8 ? 1 : 2);
    int regw = (rw < WW - WS) ? 0 : (rw < WW - 8 ? 1 : 2);
    rg[tid] = (unsigned char)(regh*3 + regw);
  }

  h8 bq[4];
  #pragma unroll
  for (int qi = 0; qi < 4; ++qi) {
    int q = wave*64 + qi*16 + ln16;
    bq[qi] = *(const h8*)(base + (size_t)q*576 + hd*32 + quad*8);
  }
  __syncthreads();

  float mrun[4], lrun[4];
  f32x4 accO[4][2];
  #pragma unroll
  for (int qi = 0; qi < 4; ++qi) {
    mrun[qi] = -1e30f; lrun[qi] = 0.f;
    #pragma unroll
    for (int r = 0; r < 4; ++r) { accO[qi][0][r] = 0.f; accO[qi][1][r] = 0.f; }
  }
  int rgq[4] = {0,0,0,0};
  if (shift > 0) {
    #pragma unroll
    for (int qi = 0; qi < 4; ++qi) rgq[qi] = rg[wave*64 + qi*16 + ln16];
  }
  const f32x4 zero4 = {0.f,0.f,0.f,0.f};

  for (int kb = 0; kb < 4; ++kb) {
    f32x4 st[4][4];
    #pragma unroll
    for (int kt = 0; kt < 4; ++kt) {
      h8 ak = *(const h8*)&Kf[kb*64 + kt*16 + ln16][quad*8];
      #pragma unroll
      for (int qi = 0; qi < 4; ++qi)
        st[kt][qi] = __builtin_amdgcn_mfma_f32_16x16x32_f16(ak, bq[qi], zero4, 0, 0, 0);
    }
    #pragma unroll
    for (int qi = 0; qi < 4; ++qi) {
      int q = wave*64 + qi*16 + ln16;
      int qrr = q >> 4, qcc = q & 15;
      float bmax = -1e30f;
      #pragma unroll
      for (int kt = 0; kt < 4; ++kt) {
        int bidx0 = (qrr - (kb*4 + kt) + 15)*31 + qcc + 15 - quad*4;
        #pragma unroll
        for (int r = 0; r < 4; ++r) {
          float s = st[kt][qi][r] + (float)rbs[bidx0 - r];
          if (shift > 0) {
            int key = kb*64 + kt*16 + quad*4 + r;
            if (rg[key] != rgq[qi]) s -= 100.f;
          }
          st[kt][qi][r] = s;
          bmax = fmaxf(bmax, s);
        }
      }
      bmax = fmaxf(bmax, __shfl_xor(bmax, 16));
      bmax = fmaxf(bmax, __shfl_xor(bmax, 32));
      float mnew  = fmaxf(mrun[qi], bmax);
      float alpha = __expf(mrun[qi] - mnew);
      mrun[qi] = mnew;
      float ps = 0.f;
      #pragma unroll
      for (int kt = 0; kt < 4; ++kt)
        #pragma unroll
        for (int r = 0; r < 4; ++r) {
          float p = __expf(st[kt][qi][r] - mnew);
          st[kt][qi][r] = p; ps += p;
        }
      ps += __shfl_xor(ps, 16);
      ps += __shfl_xor(ps, 32);
      lrun[qi] = lrun[qi]*alpha + ps;
      #pragma unroll
      for (int r = 0; r < 4; ++r) {
        float fr = __shfl(alpha, quad*4 + r);
        accO[qi][0][r] *= fr;
        accO[qi][1][r] *= fr;
      }
    }
    #pragma unroll
    for (int kt = 0; kt < 4; ++kt) {
      int kbase = kb*64 + kt*16 + quad*4;
      h4 bv0 = *(const h4*)&Vt[ln16][kbase];
      h4 bv1 = *(const h4*)&Vt[16 + ln16][kbase];
      #pragma unroll
      for (int qi = 0; qi < 4; ++qi) {
        h4 ap;
        #pragma unroll
        for (int j = 0; j < 4; ++j) ap[j] = (_Float16)st[kt][qi][j];
        accO[qi][0] = __builtin_amdgcn_mfma_f32_16x16x16f16(ap, bv0, accO[qi][0], 0, 0, 0);
        accO[qi][1] = __builtin_amdgcn_mfma_f32_16x16x16f16(ap, bv1, accO[qi][1], 0, 0, 0);
      }
    }
  }

  #pragma unroll
  for (int qi = 0; qi < 4; ++qi) {
    float linv = 1.f / lrun[qi];
    #pragma unroll
    for (int r = 0; r < 4; ++r) {
      float fr = __shfl(linv, quad*4 + r);
      int q = wave*64 + qi*16 + quad*4 + r;
      _Float16* o = OUT + (size_t)(w*NTW + q)*192 + hd*HD;
      o[ln16] = (_Float16)(accO[qi][0][r] * fr);
      if (ln16 < HD - 16) o[16 + ln16] = (_Float16)(accO[qi][1][r] * fr);
    }
  }
}

// ---------------------------------------------------------------------------
// MFMA OCAB attention, f16 Q (stride 192, pre-scaled) + f16 KV (stride 384).
// ---------------------------------------------------------------------------
__global__ __launch_bounds__(256) void ocab_attn_mfma(
    const _Float16* __restrict__ Q, const _Float16* __restrict__ KV,
    _Float16* __restrict__ OUT)
{
  constexpr int CH = 192;
  __shared__ _Float16 Kf[CH][40];
  __shared__ _Float16 Vt[32][200];
  int b = blockIdx.x;
  int w = b / HEADS, hd = b - (b / HEADS)*HEADS;
  int tid = threadIdx.x, lane = tid & 63, wave = tid >> 6;
  int quad = lane >> 4, ln16 = lane & 15;

  h8 bq[4];
  #pragma unroll
  for (int qi = 0; qi < 4; ++qi) {
    int q = wave*64 + qi*16 + ln16;
    bq[qi] = *(const h8*)(Q + (size_t)(w*NTW + q)*192 + hd*32 + quad*8);
  }

  float mrun[4], lrun[4];
  f32x4 accO[4][2];
  #pragma unroll
  for (int qi = 0; qi < 4; ++qi) {
    mrun[qi] = -1e30f; lrun[qi] = 0.f;
    #pragma unroll
    for (int r = 0; r < 4; ++r) { accO[qi][0][r] = 0.f; accO[qi][1][r] = 0.f; }
  }
  const f32x4 zero4 = {0.f,0.f,0.f,0.f};

  for (int ch = 0; ch < 3; ++ch) {
    __syncthreads();
    #pragma unroll
    for (int i = 0; i < 3; ++i) {
      int task = i*256 + tid;
      int row = task >> 2, seg = (task & 3) * 8;
      const _Float16* kvr = KV + (size_t)(w*NKV + ch*CH + row)*384;
      *(h8*)&Kf[row][seg] = *(const h8*)(kvr + hd*32 + seg);
      h8 hv = *(const h8*)(kvr + 192 + hd*32 + seg);
      #pragma unroll
      for (int j = 0; j < 8; ++j) Vt[seg + j][row] = hv[j];
    }
    __syncthreads();

    for (int kb = 0; kb < 3; ++kb) {
      f32x4 st[4][4];
      #pragma unroll
      for (int kt = 0; kt < 4; ++kt) {
        h8 ak = *(const h8*)&Kf[kb*64 + kt*16 + ln16][quad*8];
        #pragma unroll
        for (int qi = 0; qi < 4; ++qi)
          st[kt][qi] = __builtin_amdgcn_mfma_f32_16x16x32_f16(ak, bq[qi], zero4, 0, 0, 0);
      }
      #pragma unroll
      for (int qi = 0; qi < 4; ++qi) {
        float bmax = -1e30f;
        #pragma unroll
        for (int kt = 0; kt < 4; ++kt)
          #pragma unroll
          for (int r = 0; r < 4; ++r) bmax = fmaxf(bmax, st[kt][qi][r]);
        bmax = fmaxf(bmax, __shfl_xor(bmax, 16));
        bmax = fmaxf(bmax, __shfl_xor(bmax, 32));
        float mnew  = fmaxf(mrun[qi], bmax);
        float alpha = __expf(mrun[qi] - mnew);
        mrun[qi] = mnew;
        float ps = 0.f;
        #pragma unroll
        for (int kt = 0; kt < 4; ++kt)
          #pragma unroll
          for (int r = 0; r < 4; ++r) {
            float p = __expf(st[kt][qi][r] - mnew);
            st[kt][qi][r] = p; ps += p;
          }
        ps += __shfl_xor(ps, 16);
        ps += __shfl_xor(ps, 32);
        lrun[qi] = lrun[qi]*alpha + ps;
        #pragma unroll
        for (int r = 0; r < 4; ++r) {
          float fr = __shfl(alpha, quad*4 + r);
          accO[qi][0][r] *= fr;
          accO[qi][1][r] *= fr;
        }
      }
      #pragma unroll
      for (int kt = 0; kt < 4; ++kt) {
        int kbase = kb*64 + kt*16 + quad*4;
        h4 bv0 = *(const h4*)&Vt[ln16][kbase];
        h4 bv1 = *(const h4*)&Vt[16 + ln16][kbase];
        #pragma unroll
        for (int qi = 0; qi < 4; ++qi) {
          h4 ap;
          #pragma unroll
          for (int j = 0; j < 4; ++j) ap[j] = (_Float16)st[kt][qi][j];
          accO[qi][0] = __builtin_amdgcn_mfma_f32_16x16x16f16(ap, bv0, accO[qi][0], 0, 0, 0);
          accO[qi][1] = __builtin_amdgcn_mfma_f32_16x16x16f16(ap, bv1, accO[qi][1], 0, 0, 0);
        }
      }
    }
  }

  #pragma unroll
  for (int qi = 0; qi < 4; ++qi) {
    float linv = 1.f / lrun[qi];
    #pragma unroll
    for (int r = 0; r < 4; ++r) {
      float fr = __shfl(linv, quad*4 + r);
      int q = wave*64 + qi*16 + quad*4 + r;
      _Float16* o = OUT + (size_t)(w*NTW + q)*192 + hd*HD;
      o[ln16] = (_Float16)(accO[qi][0][r] * fr);
      if (ln16 < HD - 16) o[16 + ln16] = (_Float16)(accO[qi][1][r] * fr);
    }
  }
}

// ---------------------------------------------------------------------------
__global__ __launch_bounds__(256) void colsum_kernel(
    const _Float16* __restrict__ COMP, float* __restrict__ S)
{
  int tid = threadIdx.x;
  int seg = tid & 7, rb = tid >> 3;
  int row0 = blockIdx.x * 128;
  float a[8] = {};
  #pragma unroll
  for (int i = 0; i < 4; ++i) {
    int row = row0 + i*32 + rb;
    h8 v = *(const h8*)(COMP + (size_t)row*64 + seg*8);
    #pragma unroll
    for (int j = 0; j < 8; ++j) a[j] += (float)v[j];
  }
  __shared__ float sA[64];
  if (tid < 64) sA[tid] = 0.f;
  __syncthreads();
  #pragma unroll
  for (int j = 0; j < 8; ++j) atomicAdd(&sA[seg*8 + j], a[j]);
  __syncthreads();
  if (tid < 60) atomicAdd(&S[tid], sA[tid]);
}

__global__ __launch_bounds__(64) void se_kernel(
    const float* __restrict__ S, const float* __restrict__ w1,
    const float* __restrict__ b1, const float* __restrict__ w2,
    const float* __restrict__ b2, float* __restrict__ G)
{
  __shared__ float hid[CSE];
  int t = threadIdx.x;
  if (t < CSE) {
    float a = b1[t];
    for (int c = 0; c < CCH; ++c) a += (S[c] * (1.f/NT)) * w1[c * CSE + t];
    hid[t] = fmaxf(a, 0.f);
  }
  __syncthreads();
  if (t < CCH) {
    float a = b2[t];
    #pragma unroll
    for (int j = 0; j < CSE; ++j) a += hid[j] * w2[j * CCH + t];
    G[t] = 1.f / (1.f + __expf(-a));
  }
}

// ---------------------------------------------------------------------------

extern "C" void kernel_launch(void* const* d_in, const int* in_sizes, int n_in,
                              void* d_out, int out_size, void* d_ws, size_t ws_size,
                              hipStream_t stream) {
  const float* x_in   = (const float*)d_in[0];
  const float* n1w    = (const float*)d_in[1];
  const float* n1b    = (const float*)d_in[2];
  const float* qkvw   = (const float*)d_in[3];
  const float* qkvb   = (const float*)d_in[4];
  const float* relb   = (const float*)d_in[5];
  const float* projw  = (const float*)d_in[6];
  const float* projb  = (const float*)d_in[7];
  const float* ccw    = (const float*)d_in[8];
  const float* ccb    = (const float*)d_in[9];
  const float* ca1w   = (const float*)d_in[10];
  const float* ca1b   = (const float*)d_in[11];
  const float* ca2w   = (const float*)d_in[12];
  const float* ca2b   = (const float*)d_in[13];
  const float* cew    = (const float*)d_in[14];
  const float* ceb    = (const float*)d_in[15];
  const float* n2w    = (const float*)d_in[16];
  const float* n2b    = (const float*)d_in[17];
  const float* m1w    = (const float*)d_in[18];
  const float* m1b    = (const float*)d_in[19];
  const float* m2w    = (const float*)d_in[20];
  const float* m2b    = (const float*)d_in[21];
  const float* onw    = (const float*)d_in[22];
  const float* onb    = (const float*)d_in[23];
  const float* oqw    = (const float*)d_in[24];
  const float* oqb    = (const float*)d_in[25];
  const float* okvw   = (const float*)d_in[26];
  const float* okvb   = (const float*)d_in[27];
  const float* opw    = (const float*)d_in[28];
  const float* opb    = (const float*)d_in[29];
  const float* convw  = (const float*)d_in[30];
  const float* convb  = (const float*)d_in[31];

  float* ws   = (float*)d_ws;
  float*     X    = ws + OFF_X;
  _Float16*  A    = (_Float16*)(ws + OFF_A);
  _Float16*  Bq   = (_Float16*)(ws + OFF_B);
  _Float16*  COMP = (_Float16*)(ws + OFF_COMP);
  float*     S    = ws + OFF_S;
  float*     G    = ws + OFF_G;
  _Float16*  QKV  = (_Float16*)(ws + OFF_QKV);
  _Float16*  PK   = (_Float16*)(ws + OFF_PK);
  float*     PB   = ws + OFF_PB;

  float* qkvB = PB;
  float* oqB  = PB + 6*576;
  float* okvB = oqB + 192;

  const float scl = 0.18257418583505536f;

  (void)hipMemcpyAsync(X, x_in, (size_t)NT * C * sizeof(float),
                       hipMemcpyDeviceToDevice, stream);

  #define GRID(n) dim3(((n)+255)/256)
  pack_gemmw<<<GRID(6*QKV_PL), 256, 0, stream>>>(qkvw, PK+PO_QKV, 180, 540, 6, 1, 1.f, QKV_PL, 6, 180*540);
  pack_gemmw<<<GRID(6*PROJ_PL),256, 0, stream>>>(projw, PK+PO_PROJ,180, 180, 6, 0, 1.f, PROJ_PL,6, 180*180);
  pack_gemmw<<<GRID(6*M1_PL), 256, 0, stream>>>(m1w,  PK+PO_M1,  180, 360, 6, 0, 1.f, M1_PL,  6, 180*360);
  pack_gemmw<<<GRID(6*M2_PL), 256, 0, stream>>>(m2w,  PK+PO_M2,  360, 180,12, 0, 1.f, M2_PL,  6, 360*180);
  pack_gemmw<<<GRID(OQ_PL),   256, 0, stream>>>(oqw,  PK+PO_OQ,  180, 180, 6, 3, scl, OQ_PL,  1, 0);
  pack_gemmw<<<GRID(OKV_PL),  256, 0, stream>>>(okvw, PK+PO_OKV, 180, 360, 6, 2, 1.f, OKV_PL, 1, 0);
  pack_gemmw<<<GRID(OP_PL),   256, 0, stream>>>(opw,  PK+PO_OP,  180, 180, 6, 0, 1.f, OP_PL,  1, 0);
  pack_convw<<<GRID(6*CC_PL), 256, 0, stream>>>(ccw,  PK+PO_CC,  180,  60, 6, CC_PL, 6, 60*180*9);
  pack_convw<<<GRID(6*CE_PL), 256, 0, stream>>>(cew,  PK+PO_CE,   60, 180, 2, CE_PL, 6, 180*60*9);
  pack_convw<<<GRID(FIN_PL),  256, 0, stream>>>(convw,PK+PO_FIN, 180, 180, 6, FIN_PL,1, 0);
  pack_bias<<<GRID(6*576), 256, 0, stream>>>(qkvb, qkvB, 540, 576, 1, 1.f, 6);
  pack_bias<<<GRID(192),   256, 0, stream>>>(oqb,  oqB,  180, 192, 3, scl, 1);
  pack_bias<<<GRID(384),   256, 0, stream>>>(okvb, okvB, 360, 384, 2, 1.f, 1);

  const int MB128 = NT / 128;
  const int MB64  = NT / 64;

  for (int i = 0; i < DEPTH; ++i) {
    int shift = (i % 2 == 0) ? 0 : WS / 2;
    ln2_kernel<<<NT/4, 256, 0, stream>>>(X, n1w + i*C, n1b + i*C, A, 1, shift);
    gemm2<<<dim3(9, MB128), 256, 0, stream>>>(
        A, 192, PK+PO_QKV + (size_t)i*QKV_PL, qkvB + i*576,
        QKV, 576, 576, nullptr, nullptr, 180, 6, 0, 0, 0, 0);
    win_attn_mfma<<<NWIN*HEADS, 256, 0, stream>>>(
        QKV, relb + (size_t)i*961*HEADS, A, shift);
    gemm2<<<dim3(3, MB128), 256, 0, stream>>>(
        A, 192, PK+PO_PROJ + (size_t)i*PROJ_PL, projb + i*C,
        nullptr, 0, 180, X, X, 180, 6, 0, 1, 2, shift);
    conv9_mfma<<<dim3(1, MB64), 256, 0, stream>>>(
        X, nullptr, 0, PK+PO_CC + (size_t)i*CC_PL, ccb + i*CCH,
        nullptr, nullptr, nullptr, COMP, 180, 60, 6);
    (void)hipMemsetAsync(S, 0, 64*sizeof(float), stream);
    colsum_kernel<<<288, 256, 0, stream>>>(COMP, S);
    se_kernel<<<1, 64, 0, stream>>>(
        S, ca1w + (size_t)i*CCH*CSE, ca1b + (size_t)i*CSE,
        ca2w + (size_t)i*CSE*CCH, ca2b + (size_t)i*CCH, G);
    conv9_mfma<<<dim3(3, MB64), 256, 0, stream>>>(
        nullptr, COMP, 64, PK+PO_CE + (size_t)i*CE_PL, ceb + i*C,
        G, X, X, nullptr, 60, 180, 2);
    ln2_kernel<<<NT/4, 256, 0, stream>>>(X, n2w + i*C, n2b + i*C, A, 0, 0);
    gemm2<<<dim3(6, MB128), 256, 0, stream>>>(
        A, 192, PK+PO_M1 + (size_t)i*M1_PL, m1b + i*HID,
        QKV, 384, 360, nullptr, nullptr, 180, 6, 0, 0, 1, 0);
    gemm2<<<dim3(3, MB128), 256, 0, stream>>>(
        QKV, 384, PK+PO_M2 + (size_t)i*M2_PL, m2b + i*C,
        nullptr, 0, 180, X, X, 360, 12, 0, 0, 2, 0);
  }

  // ---- OCAB ----
  ln2_kernel<<<NT/4, 256, 0, stream>>>(X, onw, onb, A, 1, 0);
  gemm2<<<dim3(3, MB128), 256, 0, stream>>>(
      A, 192, PK+PO_OQ, oqB, Bq, 192, 192, nullptr, nullptr, 180, 6, 0, 0, 0, 0);
  gemm2<<<dim3(6, NWIN*NKV/128), 256, 0, stream>>>(
      A, 192, PK+PO_OKV, okvB, QKV, 384, 384, nullptr, nullptr, 180, 6, 1, 0, 0, 0);
  ocab_attn_mfma<<<NWIN*HEADS, 256, 0, stream>>>(Bq, QKV, A);
  gemm2<<<dim3(3, MB128), 256, 0, stream>>>(
      A, 192, PK+PO_OP, opb, nullptr, 0, 180, X, X, 180, 6, 0, 1, 2, 0);

  // ---- final conv + global shortcut -> d_out ----
  conv9_mfma<<<dim3(3, MB64), 256, 0, stream>>>(
      X, nullptr, 0, PK+PO_FIN, convb, nullptr, x_in,
      (float*)d_out, nullptr, 180, 180, 6);
}